// Round 1
// baseline (518.309 us; speedup 1.0000x reference)
//
#include <hip/hip_runtime.h>
#include <hip/hip_bf16.h>

typedef float f32x4 __attribute__((ext_vector_type(4)));
typedef __bf16 bf16x8 __attribute__((ext_vector_type(8)));

#define EMB 1024
#define FFD 4096
#define NHEAD 16
#define HD 64
#define SEQ 2048
#define MROWS 4096

__device__ __forceinline__ unsigned short f2bf(float f) {
    unsigned int x = __builtin_bit_cast(unsigned int, f);
    x += 0x7fffu + ((x >> 16) & 1u);
    return (unsigned short)(x >> 16);
}

__device__ __forceinline__ f32x4 mfma16(bf16x8 a, bf16x8 b, f32x4 c) {
    return __builtin_amdgcn_mfma_f32_16x16x32_bf16(a, b, c, 0, 0, 0);
}

__device__ __forceinline__ float gelu_f(float x) {
    float u = 0.7978845608028654f * (x + 0.044715f * x * x * x);
    float e = __expf(2.0f * u);
    float th = 1.0f - 2.0f / (e + 1.0f);   // tanh(u), safe at +-inf
    return 0.5f * x * (1.0f + th);
}

// ---------------------------------------------------------------------------
// GEMM: C[M,N] = A[M,K](bf16) * Bt[N,K](bf16)^T, 128x128 tile, BK=32,
// global_load_lds staging, double buffer, XOR-swizzled LDS slots.
// EPI: 0 = +bias -> bf16 ; 1 = +bias,gelu -> bf16 ; 2 = +bias+resid -> f32
// ---------------------------------------------------------------------------
template <int EPI>
__global__ __launch_bounds__(256) void gemm_bt(
    const unsigned short* __restrict__ A, const unsigned short* __restrict__ Bt,
    const float* __restrict__ bias, const float* __restrict__ resid,
    void* __restrict__ outp, int M, int N, int K)
{
    __shared__ unsigned short As[2][128 * 32];
    __shared__ unsigned short Bs[2][128 * 32];
    const int tid  = threadIdx.x;
    const int lane = tid & 63;
    const int wid  = tid >> 6;
    const int brow = blockIdx.y << 7;
    const int bcol = blockIdx.x << 7;
    const int wr = wid >> 1, wc = wid & 1;

    f32x4 acc[4][4];
    const f32x4 zero = {0.f, 0.f, 0.f, 0.f};
#pragma unroll
    for (int m = 0; m < 4; ++m)
#pragma unroll
        for (int n = 0; n < 4; ++n) acc[m][n] = zero;

    const int nk = K >> 5;

    auto stage = [&](int buf, int k0) {
#pragma unroll
        for (int c = 0; c < 2; ++c) {
            int idx = (wid << 10) + (c << 9) + (lane << 3);     // linear elem in [128*32]
            int row = idx >> 5;
            int c8s = (idx >> 3) & 3;
            int c8g = c8s ^ ((row >> 1) & 3);                   // inverse-swizzled source
            const unsigned short* ga = A  + (size_t)(brow + row) * K + k0 + (c8g << 3);
            const unsigned short* gb = Bt + (size_t)(bcol + row) * K + k0 + (c8g << 3);
            __builtin_amdgcn_global_load_lds(
                (const __attribute__((address_space(1))) unsigned int*)ga,
                (__attribute__((address_space(3))) unsigned int*)&As[buf][idx], 16, 0, 0);
            __builtin_amdgcn_global_load_lds(
                (const __attribute__((address_space(1))) unsigned int*)gb,
                (__attribute__((address_space(3))) unsigned int*)&Bs[buf][idx], 16, 0, 0);
        }
    };

    stage(0, 0);
    for (int kt = 0; kt < nk; ++kt) {
        __syncthreads();                       // buf (kt&1) ready (barrier drains vmcnt)
        if (kt + 1 < nk) stage((kt + 1) & 1, (kt + 1) << 5);
        const unsigned short* as = As[kt & 1];
        const unsigned short* bs = Bs[kt & 1];
        const int kg = lane >> 4;
        bf16x8 afr[4], bfr[4];
#pragma unroll
        for (int m = 0; m < 4; ++m) {
            int row = (wr << 6) + (m << 4) + (lane & 15);
            int c8  = kg ^ ((row >> 1) & 3);
            afr[m] = *(const bf16x8*)&as[(row << 5) + (c8 << 3)];
        }
#pragma unroll
        for (int n = 0; n < 4; ++n) {
            int row = (wc << 6) + (n << 4) + (lane & 15);
            int c8  = kg ^ ((row >> 1) & 3);
            bfr[n] = *(const bf16x8*)&bs[(row << 5) + (c8 << 3)];
        }
#pragma unroll
        for (int m = 0; m < 4; ++m)
#pragma unroll
            for (int n = 0; n < 4; ++n)
                acc[m][n] = mfma16(afr[m], bfr[n], acc[m][n]);
        __syncthreads();
    }

#pragma unroll
    for (int m = 0; m < 4; ++m) {
#pragma unroll
        for (int n = 0; n < 4; ++n) {
            const int col = bcol + (wc << 6) + (n << 4) + (lane & 15);
            const float bv = bias[col];
#pragma unroll
            for (int r = 0; r < 4; ++r) {
                const int row = brow + (wr << 6) + (m << 4) + ((lane >> 4) << 2) + r;
                float v = acc[m][n][r] + bv;
                if (EPI == 1) v = gelu_f(v);
                if (EPI == 2) {
                    ((float*)outp)[(size_t)row * N + col] = v + resid[(size_t)row * N + col];
                } else {
                    ((unsigned short*)outp)[(size_t)row * N + col] = f2bf(v);
                }
            }
        }
    }
}

// ---------------------------------------------------------------------------
// LayerNorm (unbiased std, eps added to std), f32 in -> bf16 out
// ---------------------------------------------------------------------------
__global__ __launch_bounds__(256) void layernorm_k(
    const float* __restrict__ x, const float* __restrict__ sc,
    const float* __restrict__ sh, unsigned short* __restrict__ outp)
{
    const int row = blockIdx.x;
    const int tid = threadIdx.x;
    const float4 v = ((const float4*)(x + (size_t)row * EMB))[tid];
    float s  = v.x + v.y + v.z + v.w;
    float ss = v.x * v.x + v.y * v.y + v.z * v.z + v.w * v.w;
#pragma unroll
    for (int o = 32; o > 0; o >>= 1) {
        s  += __shfl_down(s, o);
        ss += __shfl_down(ss, o);
    }
    __shared__ float red[8];
    if ((tid & 63) == 0) { red[tid >> 6] = s; red[(tid >> 6) + 4] = ss; }
    __syncthreads();
    s  = red[0] + red[1] + red[2] + red[3];
    ss = red[4] + red[5] + red[6] + red[7];
    const float mean = s * (1.0f / EMB);
    const float var  = (ss - s * mean) * (1.0f / (EMB - 1));
    const float inv  = 1.0f / (sqrtf(var) + 1e-5f);
    const int c = tid << 2;
    ushort4 o4;
    o4.x = f2bf((v.x - mean) * inv * sc[c + 0] + sh[c + 0]);
    o4.y = f2bf((v.y - mean) * inv * sc[c + 1] + sh[c + 1]);
    o4.z = f2bf((v.z - mean) * inv * sc[c + 2] + sh[c + 2]);
    o4.w = f2bf((v.w - mean) * inv * sc[c + 3] + sh[c + 3]);
    ((ushort4*)(outp + (size_t)row * EMB))[tid] = o4;
}

// ---------------------------------------------------------------------------
// Causal flash attention. Block = 4 waves; wave owns 16 q-rows; KV tiles of 64.
// qkv: [4096][3072] bf16 (q|k|v). ctx out: [4096][1024] bf16.
// ---------------------------------------------------------------------------
__global__ __launch_bounds__(256) void attn_k(
    const unsigned short* __restrict__ qkv, unsigned short* __restrict__ ctx)
{
    __shared__ unsigned short Ks[64 * 64];
    __shared__ unsigned short Vts[64 * 64];
    __shared__ unsigned short Ps[4][16 * 64];
    const int tid  = threadIdx.x;
    const int lane = tid & 63;
    const int wid  = tid >> 6;
    const int qt = blockIdx.x;      // q-tile (64 rows)
    const int h  = blockIdx.y;
    const int b  = blockIdx.z;
    const size_t rowbase = (size_t)b * SEQ;
    const int qrow0 = (qt << 6) + (wid << 4);

    bf16x8 qf[2];
    {
        const int r = qrow0 + (lane & 15);
        const int d = (lane >> 4) << 3;
        const unsigned short* qp = qkv + (rowbase + r) * 3072 + h * 64;
        qf[0] = *(const bf16x8*)&qp[d];
        qf[1] = *(const bf16x8*)&qp[32 + d];
    }

    const f32x4 zero = {0.f, 0.f, 0.f, 0.f};
    f32x4 accd[4];
#pragma unroll
    for (int g = 0; g < 4; ++g) accd[g] = zero;
    float mrow[4], lrow[4];
#pragma unroll
    for (int r = 0; r < 4; ++r) { mrow[r] = -__builtin_inff(); lrow[r] = 0.f; }

    for (int t = 0; t <= qt; ++t) {
        // stage K tile [kv][d] and V^T tile [d][kv], XOR-swizzled rows
#pragma unroll
        for (int it = 0; it < 2; ++it) {
            const int kv = (it << 5) + (tid >> 3);
            const int d8 = (tid & 7) << 3;
            const unsigned short* kp = qkv + (rowbase + (t << 6) + kv) * 3072 + EMB + h * 64 + d8;
            const uint4 kw = *(const uint4*)kp;
            *(uint4*)&Ks[(kv << 6) + (d8 ^ ((kv & 7) << 3))] = kw;
            uint4 vw = *(const uint4*)(kp + EMB);
            const unsigned short* vv = (const unsigned short*)&vw;
#pragma unroll
            for (int j = 0; j < 8; ++j) {
                const int d = d8 + j;
                Vts[(d << 6) + (kv ^ ((d & 7) << 3))] = vv[j];
            }
        }
        __syncthreads();

        // S = Q K^T * 0.125
        f32x4 sg[4];
#pragma unroll
        for (int g = 0; g < 4; ++g) {
            f32x4 sv = zero;
#pragma unroll
            for (int f = 0; f < 2; ++f) {
                const int krow = (g << 4) + (lane & 15);
                const int cb   = (f << 5) + ((lane >> 4) << 3);
                bf16x8 kf = *(const bf16x8*)&Ks[(krow << 6) + (cb ^ ((krow & 7) << 3))];
                sv = mfma16(qf[f], kf, sv);
            }
            sg[g] = sv * 0.125f;
        }
        if (t == qt) {
#pragma unroll
            for (int g = 0; g < 4; ++g) {
                const int kvg = (t << 6) + (g << 4) + (lane & 15);
#pragma unroll
                for (int r = 0; r < 4; ++r) {
                    const int qg = qrow0 + ((lane >> 4) << 2) + r;
                    if (kvg > qg) sg[g][r] = -__builtin_inff();
                }
            }
        }
        // online softmax (rows live in 16 consecutive lanes)
        float mx[4], rs[4];
#pragma unroll
        for (int r = 0; r < 4; ++r)
            mx[r] = fmaxf(fmaxf(sg[0][r], sg[1][r]), fmaxf(sg[2][r], sg[3][r]));
#pragma unroll
        for (int o = 1; o < 16; o <<= 1)
#pragma unroll
            for (int r = 0; r < 4; ++r)
                mx[r] = fmaxf(mx[r], __shfl_xor(mx[r], o));
#pragma unroll
        for (int r = 0; r < 4; ++r) {
            const float mn = fmaxf(mrow[r], mx[r]);
            const float so = __expf(mrow[r] - mn);
            mrow[r] = mn;
            lrow[r] *= so;
            rs[r] = 0.f;
#pragma unroll
            for (int g = 0; g < 4; ++g) {
                const float p = __expf(sg[g][r] - mn);
                sg[g][r] = p;
                rs[r] += p;
            }
#pragma unroll
            for (int g = 0; g < 4; ++g) accd[g][r] *= so;
        }
#pragma unroll
        for (int o = 1; o < 16; o <<= 1)
#pragma unroll
            for (int r = 0; r < 4; ++r)
                rs[r] += __shfl_xor(rs[r], o);
#pragma unroll
        for (int r = 0; r < 4; ++r) lrow[r] += rs[r];

        // P -> LDS (bf16)
#pragma unroll
        for (int g = 0; g < 4; ++g)
#pragma unroll
            for (int r = 0; r < 4; ++r) {
                const int prow = ((lane >> 4) << 2) + r;
                const int pcol = (g << 4) + (lane & 15);
                Ps[wid][(prow << 6) + (pcol ^ ((prow & 7) << 3))] = f2bf(sg[g][r]);
            }
        // ctx += P V
#pragma unroll
        for (int g = 0; g < 4; ++g) {
#pragma unroll
            for (int f = 0; f < 2; ++f) {
                const int prow = lane & 15;
                const int pcb  = (f << 5) + ((lane >> 4) << 3);
                bf16x8 pa = *(const bf16x8*)&Ps[wid][(prow << 6) + (pcb ^ ((prow & 7) << 3))];
                const int vrow = (g << 4) + (lane & 15);
                bf16x8 vb = *(const bf16x8*)&Vts[(vrow << 6) + (pcb ^ ((vrow & 7) << 3))];
                accd[g] = mfma16(pa, vb, accd[g]);
            }
        }
        __syncthreads();
    }

#pragma unroll
    for (int g = 0; g < 4; ++g)
#pragma unroll
        for (int r = 0; r < 4; ++r) {
            const size_t row = rowbase + qrow0 + ((lane >> 4) << 2) + r;
            const int col = h * 64 + (g << 4) + (lane & 15);
            ctx[row * EMB + col] = f2bf(accd[g][r] / lrow[r]);
        }
}

// ---------------------------------------------------------------------------
// W[K][N] f32 -> Wt[N][K] bf16 (tiled transpose)
// ---------------------------------------------------------------------------
__global__ __launch_bounds__(256) void transpose_cvt(
    const float* __restrict__ W, unsigned short* __restrict__ Wt, int K, int N)
{
    __shared__ float tbuf[32][33];
    const int n0 = blockIdx.x << 5;
    const int k0 = blockIdx.y << 5;
    const int tx = threadIdx.x & 31;
    const int ty = threadIdx.x >> 5;   // 0..7
#pragma unroll
    for (int j = 0; j < 32; j += 8)
        tbuf[ty + j][tx] = W[(size_t)(k0 + ty + j) * N + n0 + tx];
    __syncthreads();
#pragma unroll
    for (int j = 0; j < 32; j += 8)
        Wt[(size_t)(n0 + ty + j) * K + k0 + tx] = f2bf(tbuf[tx][ty + j]);
}

__global__ void pack_bias(const float* __restrict__ bq, const float* __restrict__ bk,
                          const float* __restrict__ bv, float* __restrict__ o)
{
    const int i = blockIdx.x * 256 + threadIdx.x;
    o[i] = (i < 1024) ? bq[i] : (i < 2048) ? bk[i - 1024] : bv[i - 2048];
}

// ---------------------------------------------------------------------------
extern "C" void kernel_launch(void* const* d_in, const int* in_sizes, int n_in,
                              void* d_out, int out_size, void* d_ws, size_t ws_size,
                              hipStream_t stream)
{
    const float* x   = (const float*)d_in[0];
    const float* l1s = (const float*)d_in[1];
    const float* l1b = (const float*)d_in[2];
    const float* l2s = (const float*)d_in[3];
    const float* l2b = (const float*)d_in[4];
    const float* wq  = (const float*)d_in[5];
    const float* bq  = (const float*)d_in[6];
    const float* wk  = (const float*)d_in[7];
    const float* bk  = (const float*)d_in[8];
    const float* wv  = (const float*)d_in[9];
    const float* bv  = (const float*)d_in[10];
    const float* wo  = (const float*)d_in[11];
    const float* bo  = (const float*)d_in[12];
    const float* wfc = (const float*)d_in[13];
    const float* bfc = (const float*)d_in[14];
    const float* wpr = (const float*)d_in[15];
    const float* bpr = (const float*)d_in[16];

    unsigned short* WtQKV = (unsigned short*)d_ws;                    // [3072][1024]
    unsigned short* WtO   = WtQKV + (size_t)3072 * 1024;              // [1024][1024]
    unsigned short* WtFC  = WtO   + (size_t)1024 * 1024;              // [4096][1024]
    unsigned short* WtPR  = WtFC  + (size_t)4096 * 1024;              // [1024][4096]
    unsigned short* LN1   = WtPR  + (size_t)1024 * 4096;              // [4096][1024]
    unsigned short* QKV   = LN1   + (size_t)4096 * 1024;              // [4096][3072]
    unsigned short* CTX   = QKV   + (size_t)4096 * 3072;              // [4096][1024]
    unsigned short* LN2   = CTX   + (size_t)4096 * 1024;              // [4096][1024]
    unsigned short* Gb    = LN2   + (size_t)4096 * 1024;              // [4096][4096]
    float* H    = (float*)(Gb + (size_t)4096 * 4096);                 // [4096][1024] f32
    float* BQKV = H + (size_t)4096 * 1024;                            // [3072]

    dim3 blk(256);
    transpose_cvt<<<dim3(32, 32), blk, 0, stream>>>(wq, WtQKV, 1024, 1024);
    transpose_cvt<<<dim3(32, 32), blk, 0, stream>>>(wk, WtQKV + (size_t)1024 * 1024, 1024, 1024);
    transpose_cvt<<<dim3(32, 32), blk, 0, stream>>>(wv, WtQKV + (size_t)2048 * 1024, 1024, 1024);
    transpose_cvt<<<dim3(32, 32), blk, 0, stream>>>(wo, WtO, 1024, 1024);
    transpose_cvt<<<dim3(128, 32), blk, 0, stream>>>(wfc, WtFC, 1024, 4096);
    transpose_cvt<<<dim3(32, 128), blk, 0, stream>>>(wpr, WtPR, 4096, 1024);
    pack_bias<<<dim3(12), blk, 0, stream>>>(bq, bk, bv, BQKV);

    layernorm_k<<<dim3(4096), blk, 0, stream>>>(x, l1s, l1b, LN1);
    gemm_bt<0><<<dim3(24, 32), blk, 0, stream>>>(LN1, WtQKV, BQKV, nullptr, QKV, 4096, 3072, 1024);
    attn_k<<<dim3(32, NHEAD, 2), blk, 0, stream>>>(QKV, CTX);
    gemm_bt<2><<<dim3(8, 32), blk, 0, stream>>>(CTX, WtO, bo, x, H, 4096, 1024, 1024);
    layernorm_k<<<dim3(4096), blk, 0, stream>>>(H, l2s, l2b, LN2);
    gemm_bt<1><<<dim3(32, 32), blk, 0, stream>>>(LN2, WtFC, bfc, nullptr, Gb, 4096, 4096, 1024);
    gemm_bt<2><<<dim3(8, 32), blk, 0, stream>>>(Gb, WtPR, bpr, H, (float*)d_out, 4096, 1024, 4096);
}

// Round 2
// 422.861 us; speedup vs baseline: 1.2257x; 1.2257x over previous
//
#include <hip/hip_runtime.h>
#include <hip/hip_bf16.h>

typedef float f32x4 __attribute__((ext_vector_type(4)));
typedef __bf16 bf16x8 __attribute__((ext_vector_type(8)));

#define EMB 1024
#define FFD 4096
#define NHEAD 16
#define HD 64
#define SEQ 2048
#define MROWS 4096

__device__ __forceinline__ unsigned short f2bf(float f) {
    unsigned int x = __builtin_bit_cast(unsigned int, f);
    x += 0x7fffu + ((x >> 16) & 1u);
    return (unsigned short)(x >> 16);
}

__device__ __forceinline__ f32x4 mfma16(bf16x8 a, bf16x8 b, f32x4 c) {
    return __builtin_amdgcn_mfma_f32_16x16x32_bf16(a, b, c, 0, 0, 0);
}

__device__ __forceinline__ float gelu_f(float x) {
    float u = 0.7978845608028654f * (x + 0.044715f * x * x * x);
    float e = __expf(2.0f * u);
    float th = 1.0f - 2.0f / (e + 1.0f);   // tanh(u), safe at +-inf
    return 0.5f * x * (1.0f + th);
}

// ---------------------------------------------------------------------------
// GEMM: C[M,N] = A[M,K](bf16) * Bt[N,K](bf16)^T, 128x128 tile, BK=32,
// global_load_lds staging, double buffer, XOR-swizzled LDS slots.
// EPI: 0 = +bias -> bf16 ; 1 = +bias,gelu -> bf16 ; 2 = +bias+resid -> f32
// ---------------------------------------------------------------------------
template <int EPI>
__global__ __launch_bounds__(256) void gemm_bt(
    const unsigned short* __restrict__ A, const unsigned short* __restrict__ Bt,
    const float* __restrict__ bias, const float* __restrict__ resid,
    void* __restrict__ outp, int M, int N, int K)
{
    __shared__ unsigned short As[2][128 * 32];
    __shared__ unsigned short Bs[2][128 * 32];
    const int tid  = threadIdx.x;
    const int lane = tid & 63;
    const int wid  = tid >> 6;
    const int brow = blockIdx.y << 7;
    const int bcol = blockIdx.x << 7;
    const int wr = wid >> 1, wc = wid & 1;

    f32x4 acc[4][4];
    const f32x4 zero = {0.f, 0.f, 0.f, 0.f};
#pragma unroll
    for (int m = 0; m < 4; ++m)
#pragma unroll
        for (int n = 0; n < 4; ++n) acc[m][n] = zero;

    const int nk = K >> 5;

    auto stage = [&](int buf, int k0) {
#pragma unroll
        for (int c = 0; c < 2; ++c) {
            int idx = (wid << 10) + (c << 9) + (lane << 3);     // linear elem in [128*32]
            int row = idx >> 5;
            int c8s = (idx >> 3) & 3;
            int c8g = c8s ^ ((row >> 1) & 3);                   // inverse-swizzled source
            const unsigned short* ga = A  + (size_t)(brow + row) * K + k0 + (c8g << 3);
            const unsigned short* gb = Bt + (size_t)(bcol + row) * K + k0 + (c8g << 3);
            __builtin_amdgcn_global_load_lds(
                (const __attribute__((address_space(1))) unsigned int*)ga,
                (__attribute__((address_space(3))) unsigned int*)&As[buf][idx], 16, 0, 0);
            __builtin_amdgcn_global_load_lds(
                (const __attribute__((address_space(1))) unsigned int*)gb,
                (__attribute__((address_space(3))) unsigned int*)&Bs[buf][idx], 16, 0, 0);
        }
    };

    stage(0, 0);
    for (int kt = 0; kt < nk; ++kt) {
        __syncthreads();                       // buf (kt&1) ready (barrier drains vmcnt)
        if (kt + 1 < nk) stage((kt + 1) & 1, (kt + 1) << 5);
        const unsigned short* as = As[kt & 1];
        const unsigned short* bs = Bs[kt & 1];
        const int kg = lane >> 4;
        bf16x8 afr[4], bfr[4];
#pragma unroll
        for (int m = 0; m < 4; ++m) {
            int row = (wr << 6) + (m << 4) + (lane & 15);
            int c8  = kg ^ ((row >> 1) & 3);
            afr[m] = *(const bf16x8*)&as[(row << 5) + (c8 << 3)];
        }
#pragma unroll
        for (int n = 0; n < 4; ++n) {
            int row = (wc << 6) + (n << 4) + (lane & 15);
            int c8  = kg ^ ((row >> 1) & 3);
            bfr[n] = *(const bf16x8*)&bs[(row << 5) + (c8 << 3)];
        }
#pragma unroll
        for (int m = 0; m < 4; ++m)
#pragma unroll
            for (int n = 0; n < 4; ++n)
                acc[m][n] = mfma16(afr[m], bfr[n], acc[m][n]);
        __syncthreads();
    }

#pragma unroll
    for (int m = 0; m < 4; ++m) {
#pragma unroll
        for (int n = 0; n < 4; ++n) {
            const int col = bcol + (wc << 6) + (n << 4) + (lane & 15);
            const float bv = bias[col];
#pragma unroll
            for (int r = 0; r < 4; ++r) {
                const int row = brow + (wr << 6) + (m << 4) + ((lane >> 4) << 2) + r;
                float v = acc[m][n][r] + bv;
                if (EPI == 1) v = gelu_f(v);
                if (EPI == 2) {
                    ((float*)outp)[(size_t)row * N + col] = v + resid[(size_t)row * N + col];
                } else {
                    ((unsigned short*)outp)[(size_t)row * N + col] = f2bf(v);
                }
            }
        }
    }
}

// ---------------------------------------------------------------------------
// LayerNorm (unbiased std, eps added to std), f32 in -> bf16 out
// ---------------------------------------------------------------------------
__global__ __launch_bounds__(256) void layernorm_k(
    const float* __restrict__ x, const float* __restrict__ sc,
    const float* __restrict__ sh, unsigned short* __restrict__ outp)
{
    const int row = blockIdx.x;
    const int tid = threadIdx.x;
    const float4 v = ((const float4*)(x + (size_t)row * EMB))[tid];
    float s  = v.x + v.y + v.z + v.w;
    float ss = v.x * v.x + v.y * v.y + v.z * v.z + v.w * v.w;
#pragma unroll
    for (int o = 32; o > 0; o >>= 1) {
        s  += __shfl_down(s, o);
        ss += __shfl_down(ss, o);
    }
    __shared__ float red[8];
    if ((tid & 63) == 0) { red[tid >> 6] = s; red[(tid >> 6) + 4] = ss; }
    __syncthreads();
    s  = red[0] + red[1] + red[2] + red[3];
    ss = red[4] + red[5] + red[6] + red[7];
    const float mean = s * (1.0f / EMB);
    const float var  = (ss - s * mean) * (1.0f / (EMB - 1));
    const float inv  = 1.0f / (sqrtf(var) + 1e-5f);
    const int c = tid << 2;
    ushort4 o4;
    o4.x = f2bf((v.x - mean) * inv * sc[c + 0] + sh[c + 0]);
    o4.y = f2bf((v.y - mean) * inv * sc[c + 1] + sh[c + 1]);
    o4.z = f2bf((v.z - mean) * inv * sc[c + 2] + sh[c + 2]);
    o4.w = f2bf((v.w - mean) * inv * sc[c + 3] + sh[c + 3]);
    ((ushort4*)(outp + (size_t)row * EMB))[tid] = o4;
}

// ---------------------------------------------------------------------------
// V transpose per head: qkv V-part [s][d] -> vt[b][h][d][s]
// ---------------------------------------------------------------------------
__global__ __launch_bounds__(256) void vtrans_k(
    const unsigned short* __restrict__ qkv, unsigned short* __restrict__ vt)
{
    __shared__ unsigned short T[64 * 64];
    const int tid = threadIdx.x;
    const int st = blockIdx.x, h = blockIdx.y, b = blockIdx.z;
    const size_t rowbase = (size_t)b * SEQ;
    const unsigned short* vsrc = qkv + (rowbase + (st << 6)) * 3072 + 2 * EMB + h * 64;
#pragma unroll
    for (int it = 0; it < 2; ++it) {
        const int s  = (it << 5) + (tid >> 3);
        const int d8 = tid & 7;
        uint4 w = *(const uint4*)(vsrc + (size_t)s * 3072 + (d8 << 3));
        *(uint4*)&T[(s << 6) + ((d8 ^ (s & 7)) << 3)] = w;
    }
    __syncthreads();
    unsigned short* vdst = vt + ((size_t)(b * NHEAD + h) << 6) * SEQ + (st << 6);
#pragma unroll
    for (int it = 0; it < 2; ++it) {
        const int d  = (it << 5) + (tid >> 3);
        const int s8 = tid & 7;
        unsigned short o8[8];
#pragma unroll
        for (int j = 0; j < 8; ++j) {
            const int s = (s8 << 3) + j;
            o8[j] = T[(s << 6) + (((d >> 3) ^ (s & 7)) << 3) + (d & 7)];
        }
        *(uint4*)(vdst + (size_t)d * SEQ + (s8 << 3)) = *(const uint4*)o8;
    }
}

// ---------------------------------------------------------------------------
// Causal flash attention. Block = 4 waves; wave owns 16 q-rows; KV tiles of 64.
// Double-buffered async staging of K (from qkv) and V^T (from vt).
// Block pairi handles q-tiles {pairi, 31-pairi} -> 33 iterations per block.
// ---------------------------------------------------------------------------
__global__ __launch_bounds__(256) void attn_k(
    const unsigned short* __restrict__ qkv, const unsigned short* __restrict__ vt,
    unsigned short* __restrict__ ctx)
{
    __shared__ unsigned short Ks[2][64 * 64];
    __shared__ unsigned short Vts[2][64 * 64];
    __shared__ unsigned short Ps[4][16 * 64];
    const int tid  = threadIdx.x;
    const int lane = tid & 63;
    const int wid  = tid >> 6;
    const int pairi = blockIdx.x;   // 0..15
    const int h  = blockIdx.y;
    const int b  = blockIdx.z;
    const size_t rowbase = (size_t)b * SEQ;
    const unsigned short* kbase = qkv + rowbase * 3072 + EMB + h * 64;       // + s*3072
    const unsigned short* vbase = vt + ((size_t)(b * NHEAD + h) << 6) * SEQ; // [d][s]

    auto stage = [&](int buf, int t) {
#pragma unroll
        for (int c = 0; c < 2; ++c) {
            const int idx = (wid << 10) + (c << 9) + (lane << 3);   // elem in [64*64]
            {   // K tile: [kv][d], swizzled 8-elem slots
                const int kv  = idx >> 6;
                const int d8s = ((idx >> 3) & 7) ^ (kv & 7);
                const unsigned short* g = kbase + (size_t)((t << 6) + kv) * 3072 + (d8s << 3);
                __builtin_amdgcn_global_load_lds(
                    (const __attribute__((address_space(1))) unsigned int*)g,
                    (__attribute__((address_space(3))) unsigned int*)&Ks[buf][idx], 16, 0, 0);
            }
            {   // V^T tile: [d][s], swizzled
                const int d   = idx >> 6;
                const int s8s = ((idx >> 3) & 7) ^ (d & 7);
                const unsigned short* g = vbase + (size_t)d * SEQ + (t << 6) + (s8s << 3);
                __builtin_amdgcn_global_load_lds(
                    (const __attribute__((address_space(1))) unsigned int*)g,
                    (__attribute__((address_space(3))) unsigned int*)&Vts[buf][idx], 16, 0, 0);
            }
        }
    };

    const f32x4 zero = {0.f, 0.f, 0.f, 0.f};

#pragma unroll 1
    for (int pass = 0; pass < 2; ++pass) {
        const int qt = pass ? (31 - pairi) : pairi;
        const int qrow0 = (qt << 6) + (wid << 4);

        bf16x8 qf[2];
        {
            const int r = qrow0 + (lane & 15);
            const int d = (lane >> 4) << 3;
            const unsigned short* qp = qkv + (rowbase + r) * 3072 + h * 64;
            qf[0] = *(const bf16x8*)&qp[d];
            qf[1] = *(const bf16x8*)&qp[32 + d];
        }

        f32x4 accd[4];
#pragma unroll
        for (int g = 0; g < 4; ++g) accd[g] = zero;
        float mrow[4], lrow[4];
#pragma unroll
        for (int r = 0; r < 4; ++r) { mrow[r] = -__builtin_inff(); lrow[r] = 0.f; }

        stage(0, 0);
#pragma unroll 1
        for (int t = 0; t <= qt; ++t) {
            __syncthreads();                   // buf (t&1) ready; prev compute done
            if (t < qt) stage((t + 1) & 1, t + 1);
            const unsigned short* ks = Ks[t & 1];
            const unsigned short* vs = Vts[t & 1];

            // S = Q K^T * 0.125
            f32x4 sg[4];
#pragma unroll
            for (int g = 0; g < 4; ++g) {
                f32x4 sv = zero;
#pragma unroll
                for (int f = 0; f < 2; ++f) {
                    const int krow = (g << 4) + (lane & 15);
                    const int cb   = (f << 5) + ((lane >> 4) << 3);
                    bf16x8 kf = *(const bf16x8*)&ks[(krow << 6) + (cb ^ ((krow & 7) << 3))];
                    sv = mfma16(qf[f], kf, sv);
                }
                sg[g] = sv * 0.125f;
            }
            if (t == qt) {
#pragma unroll
                for (int g = 0; g < 4; ++g) {
                    const int kvg = (t << 6) + (g << 4) + (lane & 15);
#pragma unroll
                    for (int r = 0; r < 4; ++r) {
                        const int qg = qrow0 + ((lane >> 4) << 2) + r;
                        if (kvg > qg) sg[g][r] = -__builtin_inff();
                    }
                }
            }
            // online softmax (rows live in 16 consecutive lanes)
            float mx[4], rs[4];
#pragma unroll
            for (int r = 0; r < 4; ++r)
                mx[r] = fmaxf(fmaxf(sg[0][r], sg[1][r]), fmaxf(sg[2][r], sg[3][r]));
#pragma unroll
            for (int o = 1; o < 16; o <<= 1)
#pragma unroll
                for (int r = 0; r < 4; ++r)
                    mx[r] = fmaxf(mx[r], __shfl_xor(mx[r], o));
#pragma unroll
            for (int r = 0; r < 4; ++r) {
                const float mn = fmaxf(mrow[r], mx[r]);
                const float so = __expf(mrow[r] - mn);
                mrow[r] = mn;
                lrow[r] *= so;
                rs[r] = 0.f;
#pragma unroll
                for (int g = 0; g < 4; ++g) {
                    const float p = __expf(sg[g][r] - mn);
                    sg[g][r] = p;
                    rs[r] += p;
                }
#pragma unroll
                for (int g = 0; g < 4; ++g) accd[g][r] *= so;
            }
#pragma unroll
            for (int o = 1; o < 16; o <<= 1)
#pragma unroll
                for (int r = 0; r < 4; ++r)
                    rs[r] += __shfl_xor(rs[r], o);
#pragma unroll
            for (int r = 0; r < 4; ++r) lrow[r] += rs[r];

            // P -> LDS (bf16)
#pragma unroll
            for (int g = 0; g < 4; ++g)
#pragma unroll
                for (int r = 0; r < 4; ++r) {
                    const int prow = ((lane >> 4) << 2) + r;
                    const int pcol = (g << 4) + (lane & 15);
                    Ps[wid][(prow << 6) + (pcol ^ ((prow & 7) << 3))] = f2bf(sg[g][r]);
                }
            // ctx += P V
#pragma unroll
            for (int g = 0; g < 4; ++g) {
#pragma unroll
                for (int f = 0; f < 2; ++f) {
                    const int prow = lane & 15;
                    const int pcb  = (f << 5) + ((lane >> 4) << 3);
                    bf16x8 pa = *(const bf16x8*)&Ps[wid][(prow << 6) + (pcb ^ ((prow & 7) << 3))];
                    const int vrow = (g << 4) + (lane & 15);
                    bf16x8 vb = *(const bf16x8*)&vs[(vrow << 6) + (pcb ^ ((vrow & 7) << 3))];
                    accd[g] = mfma16(pa, vb, accd[g]);
                }
            }
        }

#pragma unroll
        for (int g = 0; g < 4; ++g)
#pragma unroll
            for (int r = 0; r < 4; ++r) {
                const size_t row = rowbase + qrow0 + ((lane >> 4) << 2) + r;
                const int col = h * 64 + (g << 4) + (lane & 15);
                ctx[row * EMB + col] = f2bf(accd[g][r] / lrow[r]);
            }
        __syncthreads();   // protect LDS bufs before next pass's stage(0,0)
    }
}

// ---------------------------------------------------------------------------
// W[K][N] f32 -> Wt[N][K] bf16 (tiled transpose)
// ---------------------------------------------------------------------------
__global__ __launch_bounds__(256) void transpose_cvt(
    const float* __restrict__ W, unsigned short* __restrict__ Wt, int K, int N)
{
    __shared__ float tbuf[32][33];
    const int n0 = blockIdx.x << 5;
    const int k0 = blockIdx.y << 5;
    const int tx = threadIdx.x & 31;
    const int ty = threadIdx.x >> 5;   // 0..7
#pragma unroll
    for (int j = 0; j < 32; j += 8)
        tbuf[ty + j][tx] = W[(size_t)(k0 + ty + j) * N + n0 + tx];
    __syncthreads();
#pragma unroll
    for (int j = 0; j < 32; j += 8)
        Wt[(size_t)(n0 + ty + j) * K + k0 + tx] = f2bf(tbuf[tx][ty + j]);
}

__global__ void pack_bias(const float* __restrict__ bq, const float* __restrict__ bk,
                          const float* __restrict__ bv, float* __restrict__ o)
{
    const int i = blockIdx.x * 256 + threadIdx.x;
    o[i] = (i < 1024) ? bq[i] : (i < 2048) ? bk[i - 1024] : bv[i - 2048];
}

// ---------------------------------------------------------------------------
extern "C" void kernel_launch(void* const* d_in, const int* in_sizes, int n_in,
                              void* d_out, int out_size, void* d_ws, size_t ws_size,
                              hipStream_t stream)
{
    const float* x   = (const float*)d_in[0];
    const float* l1s = (const float*)d_in[1];
    const float* l1b = (const float*)d_in[2];
    const float* l2s = (const float*)d_in[3];
    const float* l2b = (const float*)d_in[4];
    const float* wq  = (const float*)d_in[5];
    const float* bq  = (const float*)d_in[6];
    const float* wk  = (const float*)d_in[7];
    const float* bk  = (const float*)d_in[8];
    const float* wv  = (const float*)d_in[9];
    const float* bv  = (const float*)d_in[10];
    const float* wo  = (const float*)d_in[11];
    const float* bo  = (const float*)d_in[12];
    const float* wfc = (const float*)d_in[13];
    const float* bfc = (const float*)d_in[14];
    const float* wpr = (const float*)d_in[15];
    const float* bpr = (const float*)d_in[16];

    unsigned short* WtQKV = (unsigned short*)d_ws;                    // [3072][1024]
    unsigned short* WtO   = WtQKV + (size_t)3072 * 1024;              // [1024][1024]
    unsigned short* WtFC  = WtO   + (size_t)1024 * 1024;              // [4096][1024]
    unsigned short* WtPR  = WtFC  + (size_t)4096 * 1024;              // [1024][4096]
    unsigned short* LN1   = WtPR  + (size_t)1024 * 4096;              // [4096][1024]
    unsigned short* QKV   = LN1   + (size_t)4096 * 1024;              // [4096][3072]
    unsigned short* CTX   = QKV   + (size_t)4096 * 3072;              // [4096][1024]
    unsigned short* LN2   = CTX   + (size_t)4096 * 1024;              // [4096][1024]
    unsigned short* Gb    = LN2   + (size_t)4096 * 1024;              // [4096][4096]
    float* H    = (float*)(Gb + (size_t)4096 * 4096);                 // [4096][1024] f32
    float* BQKV = H + (size_t)4096 * 1024;                            // [3072]
    // VT aliases Gb: VT only live between vtrans_k and attn_k; Gb written later.
    unsigned short* VT = Gb;                                          // [2*16][64][2048]

    dim3 blk(256);
    transpose_cvt<<<dim3(32, 32), blk, 0, stream>>>(wq, WtQKV, 1024, 1024);
    transpose_cvt<<<dim3(32, 32), blk, 0, stream>>>(wk, WtQKV + (size_t)1024 * 1024, 1024, 1024);
    transpose_cvt<<<dim3(32, 32), blk, 0, stream>>>(wv, WtQKV + (size_t)2048 * 1024, 1024, 1024);
    transpose_cvt<<<dim3(32, 32), blk, 0, stream>>>(wo, WtO, 1024, 1024);
    transpose_cvt<<<dim3(128, 32), blk, 0, stream>>>(wfc, WtFC, 1024, 4096);
    transpose_cvt<<<dim3(32, 128), blk, 0, stream>>>(wpr, WtPR, 4096, 1024);
    pack_bias<<<dim3(12), blk, 0, stream>>>(bq, bk, bv, BQKV);

    layernorm_k<<<dim3(4096), blk, 0, stream>>>(x, l1s, l1b, LN1);
    gemm_bt<0><<<dim3(24, 32), blk, 0, stream>>>(LN1, WtQKV, BQKV, nullptr, QKV, 4096, 3072, 1024);
    vtrans_k<<<dim3(32, NHEAD, 2), blk, 0, stream>>>(QKV, VT);
    attn_k<<<dim3(16, NHEAD, 2), blk, 0, stream>>>(QKV, VT, CTX);
    gemm_bt<2><<<dim3(8, 32), blk, 0, stream>>>(CTX, WtO, bo, x, H, 4096, 1024, 1024);
    layernorm_k<<<dim3(4096), blk, 0, stream>>>(H, l2s, l2b, LN2);
    gemm_bt<1><<<dim3(32, 32), blk, 0, stream>>>(LN2, WtFC, bfc, nullptr, Gb, 4096, 4096, 1024);
    gemm_bt<2><<<dim3(8, 32), blk, 0, stream>>>(Gb, WtPR, bpr, H, (float*)d_out, 4096, 1024, 4096);
}

// Round 6
// 410.704 us; speedup vs baseline: 1.2620x; 1.0296x over previous
//
#include <hip/hip_runtime.h>
#include <hip/hip_bf16.h>

typedef float f32x4 __attribute__((ext_vector_type(4)));
typedef __bf16 bf16x8 __attribute__((ext_vector_type(8)));

#define EMB 1024
#define FFD 4096
#define NHEAD 16
#define HD 64
#define SEQ 2048
#define MROWS 4096

__device__ __forceinline__ unsigned short f2bf(float f) {
    unsigned int x = __builtin_bit_cast(unsigned int, f);
    x += 0x7fffu + ((x >> 16) & 1u);
    return (unsigned short)(x >> 16);
}

__device__ __forceinline__ f32x4 mfma16(bf16x8 a, bf16x8 b, f32x4 c) {
    return __builtin_amdgcn_mfma_f32_16x16x32_bf16(a, b, c, 0, 0, 0);
}

__device__ __forceinline__ float gelu_f(float x) {
    float u = 0.7978845608028654f * (x + 0.044715f * x * x * x);
    float e = __expf(2.0f * u);
    float th = 1.0f - 2.0f / (e + 1.0f);   // tanh(u), safe at +-inf
    return 0.5f * x * (1.0f + th);
}

// ---------------------------------------------------------------------------
// GEMM: C[M,N] = A[M,K](bf16) * Bt[N,K](bf16)^T, 128x128 tile, BK=32,
// global_load_lds staging, double buffer, XOR-swizzled LDS slots.
// EPI: 0 = +bias -> bf16 ; 1 = +bias,gelu -> bf16
// ---------------------------------------------------------------------------
template <int EPI>
__global__ __launch_bounds__(256) void gemm_bt(
    const unsigned short* __restrict__ A, const unsigned short* __restrict__ Bt,
    const float* __restrict__ bias,
    void* __restrict__ outp, int M, int N, int K)
{
    __shared__ unsigned short As[2][128 * 32];
    __shared__ unsigned short Bs[2][128 * 32];
    const int tid  = threadIdx.x;
    const int lane = tid & 63;
    const int wid  = tid >> 6;
    const int brow = blockIdx.y << 7;
    const int bcol = blockIdx.x << 7;
    const int wr = wid >> 1, wc = wid & 1;

    f32x4 acc[4][4];
    const f32x4 zero = {0.f, 0.f, 0.f, 0.f};
#pragma unroll
    for (int m = 0; m < 4; ++m)
#pragma unroll
        for (int n = 0; n < 4; ++n) acc[m][n] = zero;

    const int nk = K >> 5;

    auto stage = [&](int buf, int k0) {
#pragma unroll
        for (int c = 0; c < 2; ++c) {
            int idx = (wid << 10) + (c << 9) + (lane << 3);     // linear elem in [128*32]
            int row = idx >> 5;
            int c8s = (idx >> 3) & 3;
            int c8g = c8s ^ ((row >> 1) & 3);                   // inverse-swizzled source
            const unsigned short* ga = A  + (size_t)(brow + row) * K + k0 + (c8g << 3);
            const unsigned short* gb = Bt + (size_t)(bcol + row) * K + k0 + (c8g << 3);
            __builtin_amdgcn_global_load_lds(
                (const __attribute__((address_space(1))) unsigned int*)ga,
                (__attribute__((address_space(3))) unsigned int*)&As[buf][idx], 16, 0, 0);
            __builtin_amdgcn_global_load_lds(
                (const __attribute__((address_space(1))) unsigned int*)gb,
                (__attribute__((address_space(3))) unsigned int*)&Bs[buf][idx], 16, 0, 0);
        }
    };

    stage(0, 0);
    for (int kt = 0; kt < nk; ++kt) {
        __syncthreads();                       // buf (kt&1) ready (barrier drains vmcnt)
        if (kt + 1 < nk) stage((kt + 1) & 1, (kt + 1) << 5);
        const unsigned short* as = As[kt & 1];
        const unsigned short* bs = Bs[kt & 1];
        const int kg = lane >> 4;
        bf16x8 afr[4], bfr[4];
#pragma unroll
        for (int m = 0; m < 4; ++m) {
            int row = (wr << 6) + (m << 4) + (lane & 15);
            int c8  = kg ^ ((row >> 1) & 3);
            afr[m] = *(const bf16x8*)&as[(row << 5) + (c8 << 3)];
        }
#pragma unroll
        for (int n = 0; n < 4; ++n) {
            int row = (wc << 6) + (n << 4) + (lane & 15);
            int c8  = kg ^ ((row >> 1) & 3);
            bfr[n] = *(const bf16x8*)&bs[(row << 5) + (c8 << 3)];
        }
#pragma unroll
        for (int m = 0; m < 4; ++m)
#pragma unroll
            for (int n = 0; n < 4; ++n)
                acc[m][n] = mfma16(afr[m], bfr[n], acc[m][n]);
        __syncthreads();
    }

#pragma unroll
    for (int m = 0; m < 4; ++m) {
#pragma unroll
        for (int n = 0; n < 4; ++n) {
            const int col = bcol + (wc << 6) + (n << 4) + (lane & 15);
            const float bv = bias[col];
#pragma unroll
            for (int r = 0; r < 4; ++r) {
                const int row = brow + (wr << 6) + (m << 4) + ((lane >> 4) << 2) + r;
                float v = acc[m][n][r] + bv;
                if (EPI == 1) v = gelu_f(v);
                ((unsigned short*)outp)[(size_t)row * N + col] = f2bf(v);
            }
        }
    }
}

// ---------------------------------------------------------------------------
// Narrow-N GEMM: BM=128, BN=64, BK=32. 4 waves, each 32 rows x 64 cols.
// Deterministic single-write epilogue: out = A*Bt^T + bias + resid (f32).
// Grid: (N/64, M/128). Higher occupancy for N=1024 shapes (2+ blocks/CU).
// ---------------------------------------------------------------------------
__global__ __launch_bounds__(256) void gemm_bt_n64(
    const unsigned short* __restrict__ A, const unsigned short* __restrict__ Bt,
    const float* __restrict__ bias, const float* __restrict__ resid,
    float* __restrict__ outp, int M, int N, int K)
{
    __shared__ unsigned short As[2][128 * 32];
    __shared__ unsigned short Bs[2][64 * 32];
    const int tid  = threadIdx.x;
    const int lane = tid & 63;
    const int wid  = tid >> 6;
    const int brow = blockIdx.y << 7;
    const int bcol = blockIdx.x << 6;

    f32x4 acc[2][4];
    const f32x4 zero = {0.f, 0.f, 0.f, 0.f};
#pragma unroll
    for (int m = 0; m < 2; ++m)
#pragma unroll
        for (int n = 0; n < 4; ++n) acc[m][n] = zero;

    const int nk = K >> 5;

    auto stage = [&](int buf, int k0) {
#pragma unroll
        for (int c = 0; c < 2; ++c) {           // A tile: 128*32 = 2 rounds
            int idx = (wid << 10) + (c << 9) + (lane << 3);
            int row = idx >> 5;
            int c8g = ((idx >> 3) & 3) ^ ((row >> 1) & 3);
            const unsigned short* ga = A + (size_t)(brow + row) * K + k0 + (c8g << 3);
            __builtin_amdgcn_global_load_lds(
                (const __attribute__((address_space(1))) unsigned int*)ga,
                (__attribute__((address_space(3))) unsigned int*)&As[buf][idx], 16, 0, 0);
        }
        {                                        // B tile: 64*32 = 1 round
            int idx = tid << 3;
            int row = idx >> 5;
            int c8g = ((idx >> 3) & 3) ^ ((row >> 1) & 3);
            const unsigned short* gb = Bt + (size_t)(bcol + row) * K + k0 + (c8g << 3);
            __builtin_amdgcn_global_load_lds(
                (const __attribute__((address_space(1))) unsigned int*)gb,
                (__attribute__((address_space(3))) unsigned int*)&Bs[buf][idx], 16, 0, 0);
        }
    };

    stage(0, 0);
    for (int kt = 0; kt < nk; ++kt) {
        __syncthreads();
        if (kt + 1 < nk) stage((kt + 1) & 1, (kt + 1) << 5);
        const unsigned short* as = As[kt & 1];
        const unsigned short* bs = Bs[kt & 1];
        const int kg = lane >> 4;
        bf16x8 afr[2], bfr[4];
#pragma unroll
        for (int m = 0; m < 2; ++m) {
            int row = (wid << 5) + (m << 4) + (lane & 15);
            int c8  = kg ^ ((row >> 1) & 3);
            afr[m] = *(const bf16x8*)&as[(row << 5) + (c8 << 3)];
        }
#pragma unroll
        for (int n = 0; n < 4; ++n) {
            int row = (n << 4) + (lane & 15);
            int c8  = kg ^ ((row >> 1) & 3);
            bfr[n] = *(const bf16x8*)&bs[(row << 5) + (c8 << 3)];
        }
#pragma unroll
        for (int m = 0; m < 2; ++m)
#pragma unroll
            for (int n = 0; n < 4; ++n)
                acc[m][n] = mfma16(afr[m], bfr[n], acc[m][n]);
        __syncthreads();
    }

#pragma unroll
    for (int m = 0; m < 2; ++m)
#pragma unroll
        for (int n = 0; n < 4; ++n) {
            const int col = bcol + (n << 4) + (lane & 15);
            const float bv = bias[col];
#pragma unroll
            for (int r = 0; r < 4; ++r) {
                const int row = brow + (wid << 5) + (m << 4) + ((lane >> 4) << 2) + r;
                outp[(size_t)row * N + col] =
                    acc[m][n][r] + bv + resid[(size_t)row * N + col];
            }
        }
}

// ---------------------------------------------------------------------------
// LayerNorm (unbiased std, eps added to std), f32 in -> bf16 out
// ---------------------------------------------------------------------------
__global__ __launch_bounds__(256) void layernorm_k(
    const float* __restrict__ x, const float* __restrict__ sc,
    const float* __restrict__ sh, unsigned short* __restrict__ outp)
{
    const int row = blockIdx.x;
    const int tid = threadIdx.x;
    const float4 v = ((const float4*)(x + (size_t)row * EMB))[tid];
    float s  = v.x + v.y + v.z + v.w;
    float ss = v.x * v.x + v.y * v.y + v.z * v.z + v.w * v.w;
#pragma unroll
    for (int o = 32; o > 0; o >>= 1) {
        s  += __shfl_down(s, o);
        ss += __shfl_down(ss, o);
    }
    __shared__ float red[8];
    if ((tid & 63) == 0) { red[tid >> 6] = s; red[(tid >> 6) + 4] = ss; }
    __syncthreads();
    s  = red[0] + red[1] + red[2] + red[3];
    ss = red[4] + red[5] + red[6] + red[7];
    const float mean = s * (1.0f / EMB);
    const float var  = (ss - s * mean) * (1.0f / (EMB - 1));
    const float inv  = 1.0f / (sqrtf(var) + 1e-5f);
    const int c = tid << 2;
    ushort4 o4;
    o4.x = f2bf((v.x - mean) * inv * sc[c + 0] + sh[c + 0]);
    o4.y = f2bf((v.y - mean) * inv * sc[c + 1] + sh[c + 1]);
    o4.z = f2bf((v.z - mean) * inv * sc[c + 2] + sh[c + 2]);
    o4.w = f2bf((v.w - mean) * inv * sc[c + 3] + sh[c + 3]);
    ((ushort4*)(outp + (size_t)row * EMB))[tid] = o4;
}

// ---------------------------------------------------------------------------
// V transpose per head: qkv V-part [s][d] -> vt[b][h][d][s]
// ---------------------------------------------------------------------------
__global__ __launch_bounds__(256) void vtrans_k(
    const unsigned short* __restrict__ qkv, unsigned short* __restrict__ vt)
{
    __shared__ unsigned short T[64 * 64];
    const int tid = threadIdx.x;
    const int st = blockIdx.x, h = blockIdx.y, b = blockIdx.z;
    const size_t rowbase = (size_t)b * SEQ;
    const unsigned short* vsrc = qkv + (rowbase + (st << 6)) * 3072 + 2 * EMB + h * 64;
#pragma unroll
    for (int it = 0; it < 2; ++it) {
        const int s  = (it << 5) + (tid >> 3);
        const int d8 = tid & 7;
        uint4 w = *(const uint4*)(vsrc + (size_t)s * 3072 + (d8 << 3));
        *(uint4*)&T[(s << 6) + ((d8 ^ (s & 7)) << 3)] = w;
    }
    __syncthreads();
    unsigned short* vdst = vt + ((size_t)(b * NHEAD + h) << 6) * SEQ + (st << 6);
#pragma unroll
    for (int it = 0; it < 2; ++it) {
        const int d  = (it << 5) + (tid >> 3);
        const int s8 = tid & 7;
        unsigned short o8[8];
#pragma unroll
        for (int j = 0; j < 8; ++j) {
            const int s = (s8 << 3) + j;
            o8[j] = T[(s << 6) + (((d >> 3) ^ (s & 7)) << 3) + (d & 7)];
        }
        *(uint4*)(vdst + (size_t)d * SEQ + (s8 << 3)) = *(const uint4*)o8;
    }
}

// ---------------------------------------------------------------------------
// Causal flash attention. Block = 4 waves; wave owns 16 q-rows; KV tiles of 64.
// Double-buffered async staging of K (from qkv) and V^T (from vt).
// Block pairi handles q-tiles {pairi, 31-pairi} -> 33 iterations per block.
// ---------------------------------------------------------------------------
__global__ __launch_bounds__(256) void attn_k(
    const unsigned short* __restrict__ qkv, const unsigned short* __restrict__ vt,
    unsigned short* __restrict__ ctx)
{
    __shared__ unsigned short Ks[2][64 * 64];
    __shared__ unsigned short Vts[2][64 * 64];
    __shared__ unsigned short Ps[4][16 * 64];
    const int tid  = threadIdx.x;
    const int lane = tid & 63;
    const int wid  = tid >> 6;
    const int pairi = blockIdx.x;   // 0..15
    const int h  = blockIdx.y;
    const int b  = blockIdx.z;
    const size_t rowbase = (size_t)b * SEQ;
    const unsigned short* kbase = qkv + rowbase * 3072 + EMB + h * 64;       // + s*3072
    const unsigned short* vbase = vt + ((size_t)(b * NHEAD + h) << 6) * SEQ; // [d][s]

    auto stage = [&](int buf, int t) {
#pragma unroll
        for (int c = 0; c < 2; ++c) {
            const int idx = (wid << 10) + (c << 9) + (lane << 3);   // elem in [64*64]
            {   // K tile: [kv][d], swizzled 8-elem slots
                const int kv  = idx >> 6;
                const int d8s = ((idx >> 3) & 7) ^ (kv & 7);
                const unsigned short* g = kbase + (size_t)((t << 6) + kv) * 3072 + (d8s << 3);
                __builtin_amdgcn_global_load_lds(
                    (const __attribute__((address_space(1))) unsigned int*)g,
                    (__attribute__((address_space(3))) unsigned int*)&Ks[buf][idx], 16, 0, 0);
            }
            {   // V^T tile: [d][s], swizzled
                const int d   = idx >> 6;
                const int s8s = ((idx >> 3) & 7) ^ (d & 7);
                const unsigned short* g = vbase + (size_t)d * SEQ + (t << 6) + (s8s << 3);
                __builtin_amdgcn_global_load_lds(
                    (const __attribute__((address_space(1))) unsigned int*)g,
                    (__attribute__((address_space(3))) unsigned int*)&Vts[buf][idx], 16, 0, 0);
            }
        }
    };

    const f32x4 zero = {0.f, 0.f, 0.f, 0.f};

#pragma unroll 1
    for (int pass = 0; pass < 2; ++pass) {
        const int qt = pass ? (31 - pairi) : pairi;
        const int qrow0 = (qt << 6) + (wid << 4);

        bf16x8 qf[2];
        {
            const int r = qrow0 + (lane & 15);
            const int d = (lane >> 4) << 3;
            const unsigned short* qp = qkv + (rowbase + r) * 3072 + h * 64;
            qf[0] = *(const bf16x8*)&qp[d];
            qf[1] = *(const bf16x8*)&qp[32 + d];
        }

        f32x4 accd[4];
#pragma unroll
        for (int g = 0; g < 4; ++g) accd[g] = zero;
        float mrow[4], lrow[4];
#pragma unroll
        for (int r = 0; r < 4; ++r) { mrow[r] = -__builtin_inff(); lrow[r] = 0.f; }

        stage(0, 0);
#pragma unroll 1
        for (int t = 0; t <= qt; ++t) {
            __syncthreads();                   // buf (t&1) ready; prev compute done
            if (t < qt) stage((t + 1) & 1, t + 1);
            const unsigned short* ks = Ks[t & 1];
            const unsigned short* vs = Vts[t & 1];

            // S = Q K^T * 0.125
            f32x4 sg[4];
#pragma unroll
            for (int g = 0; g < 4; ++g) {
                f32x4 sv = zero;
#pragma unroll
                for (int f = 0; f < 2; ++f) {
                    const int krow = (g << 4) + (lane & 15);
                    const int cb   = (f << 5) + ((lane >> 4) << 3);
                    bf16x8 kf = *(const bf16x8*)&ks[(krow << 6) + (cb ^ ((krow & 7) << 3))];
                    sv = mfma16(qf[f], kf, sv);
                }
                sg[g] = sv * 0.125f;
            }
            if (t == qt) {
#pragma unroll
                for (int g = 0; g < 4; ++g) {
                    const int kvg = (t << 6) + (g << 4) + (lane & 15);
#pragma unroll
                    for (int r = 0; r < 4; ++r) {
                        const int qg = qrow0 + ((lane >> 4) << 2) + r;
                        if (kvg > qg) sg[g][r] = -__builtin_inff();
                    }
                }
            }
            // online softmax (rows live in 16 consecutive lanes)
            float mx[4], rs[4];
#pragma unroll
            for (int r = 0; r < 4; ++r)
                mx[r] = fmaxf(fmaxf(sg[0][r], sg[1][r]), fmaxf(sg[2][r], sg[3][r]));
#pragma unroll
            for (int o = 1; o < 16; o <<= 1)
#pragma unroll
                for (int r = 0; r < 4; ++r)
                    mx[r] = fmaxf(mx[r], __shfl_xor(mx[r], o));
#pragma unroll
            for (int r = 0; r < 4; ++r) {
                const float mn = fmaxf(mrow[r], mx[r]);
                const float so = __expf(mrow[r] - mn);
                mrow[r] = mn;
                lrow[r] *= so;
                rs[r] = 0.f;
#pragma unroll
                for (int g = 0; g < 4; ++g) {
                    const float p = __expf(sg[g][r] - mn);
                    sg[g][r] = p;
                    rs[r] += p;
                }
#pragma unroll
                for (int g = 0; g < 4; ++g) accd[g][r] *= so;
            }
#pragma unroll
            for (int o = 1; o < 16; o <<= 1)
#pragma unroll
                for (int r = 0; r < 4; ++r)
                    rs[r] += __shfl_xor(rs[r], o);
#pragma unroll
            for (int r = 0; r < 4; ++r) lrow[r] += rs[r];

            // P -> LDS (bf16)
#pragma unroll
            for (int g = 0; g < 4; ++g)
#pragma unroll
                for (int r = 0; r < 4; ++r) {
                    const int prow = ((lane >> 4) << 2) + r;
                    const int pcol = (g << 4) + (lane & 15);
                    Ps[wid][(prow << 6) + (pcol ^ ((prow & 7) << 3))] = f2bf(sg[g][r]);
                }
            // ctx += P V
#pragma unroll
            for (int g = 0; g < 4; ++g) {
#pragma unroll
                for (int f = 0; f < 2; ++f) {
                    const int prow = lane & 15;
                    const int pcb  = (f << 5) + ((lane >> 4) << 3);
                    bf16x8 pa = *(const bf16x8*)&Ps[wid][(prow << 6) + (pcb ^ ((prow & 7) << 3))];
                    const int vrow = (g << 4) + (lane & 15);
                    bf16x8 vb = *(const bf16x8*)&vs[(vrow << 6) + (pcb ^ ((vrow & 7) << 3))];
                    accd[g] = mfma16(pa, vb, accd[g]);
                }
            }
        }

#pragma unroll
        for (int g = 0; g < 4; ++g)
#pragma unroll
            for (int r = 0; r < 4; ++r) {
                const size_t row = rowbase + qrow0 + ((lane >> 4) << 2) + r;
                const int col = h * 64 + (g << 4) + (lane & 15);
                ctx[row * EMB + col] = f2bf(accd[g][r] / lrow[r]);
            }
        __syncthreads();   // protect LDS bufs before next pass's stage(0,0)
    }
}

// ---------------------------------------------------------------------------
// W[K][N] f32 -> Wt[N][K] bf16 (tiled transpose)
// ---------------------------------------------------------------------------
__global__ __launch_bounds__(256) void transpose_cvt(
    const float* __restrict__ W, unsigned short* __restrict__ Wt, int K, int N)
{
    __shared__ float tbuf[32][33];
    const int n0 = blockIdx.x << 5;
    const int k0 = blockIdx.y << 5;
    const int tx = threadIdx.x & 31;
    const int ty = threadIdx.x >> 5;   // 0..7
#pragma unroll
    for (int j = 0; j < 32; j += 8)
        tbuf[ty + j][tx] = W[(size_t)(k0 + ty + j) * N + n0 + tx];
    __syncthreads();
#pragma unroll
    for (int j = 0; j < 32; j += 8)
        Wt[(size_t)(n0 + ty + j) * K + k0 + tx] = f2bf(tbuf[tx][ty + j]);
}

__global__ void pack_bias(const float* __restrict__ bq, const float* __restrict__ bk,
                          const float* __restrict__ bv, float* __restrict__ o)
{
    const int i = blockIdx.x * 256 + threadIdx.x;
    o[i] = (i < 1024) ? bq[i] : (i < 2048) ? bk[i - 1024] : bv[i - 2048];
}

// ---------------------------------------------------------------------------
extern "C" void kernel_launch(void* const* d_in, const int* in_sizes, int n_in,
                              void* d_out, int out_size, void* d_ws, size_t ws_size,
                              hipStream_t stream)
{
    const float* x   = (const float*)d_in[0];
    const float* l1s = (const float*)d_in[1];
    const float* l1b = (const float*)d_in[2];
    const float* l2s = (const float*)d_in[3];
    const float* l2b = (const float*)d_in[4];
    const float* wq  = (const float*)d_in[5];
    const float* bq  = (const float*)d_in[6];
    const float* wk  = (const float*)d_in[7];
    const float* bk  = (const float*)d_in[8];
    const float* wv  = (const float*)d_in[9];
    const float* bv  = (const float*)d_in[10];
    const float* wo  = (const float*)d_in[11];
    const float* bo  = (const float*)d_in[12];
    const float* wfc = (const float*)d_in[13];
    const float* bfc = (const float*)d_in[14];
    const float* wpr = (const float*)d_in[15];
    const float* bpr = (const float*)d_in[16];

    unsigned short* WtQKV = (unsigned short*)d_ws;                    // [3072][1024]
    unsigned short* WtO   = WtQKV + (size_t)3072 * 1024;              // [1024][1024]
    unsigned short* WtFC  = WtO   + (size_t)1024 * 1024;              // [4096][1024]
    unsigned short* WtPR  = WtFC  + (size_t)4096 * 1024;              // [1024][4096]
    unsigned short* LN1   = WtPR  + (size_t)1024 * 4096;              // [4096][1024]
    unsigned short* QKV   = LN1   + (size_t)4096 * 1024;              // [4096][3072]
    unsigned short* CTX   = QKV   + (size_t)4096 * 3072;              // [4096][1024]
    unsigned short* LN2   = CTX   + (size_t)4096 * 1024;              // [4096][1024]
    unsigned short* Gb    = LN2   + (size_t)4096 * 1024;              // [4096][4096]
    float* H    = (float*)(Gb + (size_t)4096 * 4096);                 // [4096][1024] f32
    float* BQKV = H + (size_t)4096 * 1024;                            // [3072]
    // VT aliases Gb: VT only live between vtrans_k and attn_k; Gb written later.
    unsigned short* VT = Gb;                                          // [2*16][64][2048]

    dim3 blk(256);
    transpose_cvt<<<dim3(32, 32), blk, 0, stream>>>(wq, WtQKV, 1024, 1024);
    transpose_cvt<<<dim3(32, 32), blk, 0, stream>>>(wk, WtQKV + (size_t)1024 * 1024, 1024, 1024);
    transpose_cvt<<<dim3(32, 32), blk, 0, stream>>>(wv, WtQKV + (size_t)2048 * 1024, 1024, 1024);
    transpose_cvt<<<dim3(32, 32), blk, 0, stream>>>(wo, WtO, 1024, 1024);
    transpose_cvt<<<dim3(128, 32), blk, 0, stream>>>(wfc, WtFC, 1024, 4096);
    transpose_cvt<<<dim3(32, 128), blk, 0, stream>>>(wpr, WtPR, 4096, 1024);
    pack_bias<<<dim3(12), blk, 0, stream>>>(bq, bk, bv, BQKV);

    layernorm_k<<<dim3(4096), blk, 0, stream>>>(x, l1s, l1b, LN1);
    gemm_bt<0><<<dim3(24, 32), blk, 0, stream>>>(LN1, WtQKV, BQKV, QKV, 4096, 3072, 1024);
    vtrans_k<<<dim3(32, NHEAD, 2), blk, 0, stream>>>(QKV, VT);
    attn_k<<<dim3(16, NHEAD, 2), blk, 0, stream>>>(QKV, VT, CTX);
    // H = CTX @ WoT + bo + x   (BN=64 tile, 512 blocks)
    gemm_bt_n64<<<dim3(16, 32), blk, 0, stream>>>(CTX, WtO, bo, x, H, 4096, 1024, 1024);
    layernorm_k<<<dim3(4096), blk, 0, stream>>>(H, l2s, l2b, LN2);
    gemm_bt<1><<<dim3(32, 32), blk, 0, stream>>>(LN2, WtFC, bfc, Gb, 4096, 4096, 1024);
    // d_out = Gb @ WprT + bpr + H   (BN=64 tile, 512 blocks)
    gemm_bt_n64<<<dim3(16, 32), blk, 0, stream>>>(Gb, WtPR, bpr, H, (float*)d_out, 4096, 1024, 4096);
}

// Round 7
// 393.019 us; speedup vs baseline: 1.3188x; 1.0450x over previous
//
#include <hip/hip_runtime.h>
#include <hip/hip_bf16.h>

typedef float f32x4 __attribute__((ext_vector_type(4)));
typedef __bf16 bf16x8 __attribute__((ext_vector_type(8)));

#define EMB 1024
#define FFD 4096
#define NHEAD 16
#define HD 64
#define SEQ 2048
#define MROWS 4096

__device__ __forceinline__ unsigned short f2bf(float f) {
    unsigned int x = __builtin_bit_cast(unsigned int, f);
    x += 0x7fffu + ((x >> 16) & 1u);
    return (unsigned short)(x >> 16);
}

__device__ __forceinline__ unsigned int pack2bf(float a, float b) {
    return (unsigned int)f2bf(a) | ((unsigned int)f2bf(b) << 16);
}

__device__ __forceinline__ f32x4 mfma16(bf16x8 a, bf16x8 b, f32x4 c) {
    return __builtin_amdgcn_mfma_f32_16x16x32_bf16(a, b, c, 0, 0, 0);
}

__device__ __forceinline__ bf16x8 scale8(bf16x8 v, float s) {
    bf16x8 o;
#pragma unroll
    for (int i = 0; i < 8; ++i) o[i] = (__bf16)((float)v[i] * s);
    return o;
}

__device__ __forceinline__ float gelu_f(float x) {
    float u = 0.7978845608028654f * (x + 0.044715f * x * x * x);
    float e = __expf(2.0f * u);
    float th = 1.0f - 2.0f / (e + 1.0f);   // tanh(u), safe at +-inf
    return 0.5f * x * (1.0f + th);
}

// XCD-grouping remap: blocks sharing `by` (A-panel) land on the same XCD.
// Requires gridDim.y % 8 == 0 (and total % 8 == 0).
__device__ __forceinline__ void xcd_remap(int& bx, int& by) {
    const int nbx = gridDim.x;
    int id = blockIdx.x + nbx * blockIdx.y;
    int xcd = id & 7, i = id >> 3;
    by = (i / nbx) * 8 + xcd;
    bx = i % nbx;
}

// ---------------------------------------------------------------------------
// GEMM: C[M,N] = A[M,K](bf16) * Bt[N,K](bf16)^T, 128x128 tile, BK=32,
// global_load_lds staging, double buffer, XOR-swizzled LDS slots.
// EPI: 0 = +bias -> bf16 ; 1 = +bias,gelu -> bf16
// ---------------------------------------------------------------------------
template <int EPI>
__global__ __launch_bounds__(256) void gemm_bt(
    const unsigned short* __restrict__ A, const unsigned short* __restrict__ Bt,
    const float* __restrict__ bias,
    void* __restrict__ outp, int M, int N, int K)
{
    __shared__ unsigned short As[2][128 * 32];
    __shared__ unsigned short Bs[2][128 * 32];
    const int tid  = threadIdx.x;
    const int lane = tid & 63;
    const int wid  = tid >> 6;
    int bx, by; xcd_remap(bx, by);
    const int brow = by << 7;
    const int bcol = bx << 7;
    const int wr = wid >> 1, wc = wid & 1;

    f32x4 acc[4][4];
    const f32x4 zero = {0.f, 0.f, 0.f, 0.f};
#pragma unroll
    for (int m = 0; m < 4; ++m)
#pragma unroll
        for (int n = 0; n < 4; ++n) acc[m][n] = zero;

    const int nk = K >> 5;

    auto stage = [&](int buf, int k0) {
#pragma unroll
        for (int c = 0; c < 2; ++c) {
            int idx = (wid << 10) + (c << 9) + (lane << 3);     // linear elem in [128*32]
            int row = idx >> 5;
            int c8s = (idx >> 3) & 3;
            int c8g = c8s ^ ((row >> 1) & 3);                   // inverse-swizzled source
            const unsigned short* ga = A  + (size_t)(brow + row) * K + k0 + (c8g << 3);
            const unsigned short* gb = Bt + (size_t)(bcol + row) * K + k0 + (c8g << 3);
            __builtin_amdgcn_global_load_lds(
                (const __attribute__((address_space(1))) unsigned int*)ga,
                (__attribute__((address_space(3))) unsigned int*)&As[buf][idx], 16, 0, 0);
            __builtin_amdgcn_global_load_lds(
                (const __attribute__((address_space(1))) unsigned int*)gb,
                (__attribute__((address_space(3))) unsigned int*)&Bs[buf][idx], 16, 0, 0);
        }
    };

    stage(0, 0);
    for (int kt = 0; kt < nk; ++kt) {
        __syncthreads();                       // buf (kt&1) ready (barrier drains vmcnt)
        if (kt + 1 < nk) stage((kt + 1) & 1, (kt + 1) << 5);
        const unsigned short* as = As[kt & 1];
        const unsigned short* bs = Bs[kt & 1];
        const int kg = lane >> 4;
        bf16x8 afr[4], bfr[4];
#pragma unroll
        for (int m = 0; m < 4; ++m) {
            int row = (wr << 6) + (m << 4) + (lane & 15);
            int c8  = kg ^ ((row >> 1) & 3);
            afr[m] = *(const bf16x8*)&as[(row << 5) + (c8 << 3)];
        }
#pragma unroll
        for (int n = 0; n < 4; ++n) {
            int row = (wc << 6) + (n << 4) + (lane & 15);
            int c8  = kg ^ ((row >> 1) & 3);
            bfr[n] = *(const bf16x8*)&bs[(row << 5) + (c8 << 3)];
        }
#pragma unroll
        for (int m = 0; m < 4; ++m)
#pragma unroll
            for (int n = 0; n < 4; ++n)
                acc[m][n] = mfma16(afr[m], bfr[n], acc[m][n]);
        __syncthreads();
    }

#pragma unroll
    for (int m = 0; m < 4; ++m) {
#pragma unroll
        for (int n = 0; n < 4; ++n) {
            const int col = bcol + (wc << 6) + (n << 4) + (lane & 15);
            const float bv = bias[col];
#pragma unroll
            for (int r = 0; r < 4; ++r) {
                const int row = brow + (wr << 6) + (m << 4) + ((lane >> 4) << 2) + r;
                float v = acc[m][n][r] + bv;
                if (EPI == 1) v = gelu_f(v);
                ((unsigned short*)outp)[(size_t)row * N + col] = f2bf(v);
            }
        }
    }
}

// ---------------------------------------------------------------------------
// Narrow-N GEMM: BM=128, BN=64, BK=32. 4 waves, each 32 rows x 64 cols.
// Deterministic single-write epilogue: out = A*Bt^T + bias + resid (f32).
// ---------------------------------------------------------------------------
__global__ __launch_bounds__(256) void gemm_bt_n64(
    const unsigned short* __restrict__ A, const unsigned short* __restrict__ Bt,
    const float* __restrict__ bias, const float* __restrict__ resid,
    float* __restrict__ outp, int M, int N, int K)
{
    __shared__ unsigned short As[2][128 * 32];
    __shared__ unsigned short Bs[2][64 * 32];
    const int tid  = threadIdx.x;
    const int lane = tid & 63;
    const int wid  = tid >> 6;
    int bx, by; xcd_remap(bx, by);
    const int brow = by << 7;
    const int bcol = bx << 6;

    f32x4 acc[2][4];
    const f32x4 zero = {0.f, 0.f, 0.f, 0.f};
#pragma unroll
    for (int m = 0; m < 2; ++m)
#pragma unroll
        for (int n = 0; n < 4; ++n) acc[m][n] = zero;

    const int nk = K >> 5;

    auto stage = [&](int buf, int k0) {
#pragma unroll
        for (int c = 0; c < 2; ++c) {           // A tile: 128*32 = 2 rounds
            int idx = (wid << 10) + (c << 9) + (lane << 3);
            int row = idx >> 5;
            int c8g = ((idx >> 3) & 3) ^ ((row >> 1) & 3);
            const unsigned short* ga = A + (size_t)(brow + row) * K + k0 + (c8g << 3);
            __builtin_amdgcn_global_load_lds(
                (const __attribute__((address_space(1))) unsigned int*)ga,
                (__attribute__((address_space(3))) unsigned int*)&As[buf][idx], 16, 0, 0);
        }
        {                                        // B tile: 64*32 = 1 round
            int idx = tid << 3;
            int row = idx >> 5;
            int c8g = ((idx >> 3) & 3) ^ ((row >> 1) & 3);
            const unsigned short* gb = Bt + (size_t)(bcol + row) * K + k0 + (c8g << 3);
            __builtin_amdgcn_global_load_lds(
                (const __attribute__((address_space(1))) unsigned int*)gb,
                (__attribute__((address_space(3))) unsigned int*)&Bs[buf][idx], 16, 0, 0);
        }
    };

    stage(0, 0);
    for (int kt = 0; kt < nk; ++kt) {
        __syncthreads();
        if (kt + 1 < nk) stage((kt + 1) & 1, (kt + 1) << 5);
        const unsigned short* as = As[kt & 1];
        const unsigned short* bs = Bs[kt & 1];
        const int kg = lane >> 4;
        bf16x8 afr[2], bfr[4];
#pragma unroll
        for (int m = 0; m < 2; ++m) {
            int row = (wid << 5) + (m << 4) + (lane & 15);
            int c8  = kg ^ ((row >> 1) & 3);
            afr[m] = *(const bf16x8*)&as[(row << 5) + (c8 << 3)];
        }
#pragma unroll
        for (int n = 0; n < 4; ++n) {
            int row = (n << 4) + (lane & 15);
            int c8  = kg ^ ((row >> 1) & 3);
            bfr[n] = *(const bf16x8*)&bs[(row << 5) + (c8 << 3)];
        }
#pragma unroll
        for (int m = 0; m < 2; ++m)
#pragma unroll
            for (int n = 0; n < 4; ++n)
                acc[m][n] = mfma16(afr[m], bfr[n], acc[m][n]);
        __syncthreads();
    }

#pragma unroll
    for (int m = 0; m < 2; ++m)
#pragma unroll
        for (int n = 0; n < 4; ++n) {
            const int col = bcol + (n << 4) + (lane & 15);
            const float bv = bias[col];
#pragma unroll
            for (int r = 0; r < 4; ++r) {
                const int row = brow + (wid << 5) + (m << 4) + ((lane >> 4) << 2) + r;
                outp[(size_t)row * N + col] =
                    acc[m][n][r] + bv + resid[(size_t)row * N + col];
            }
        }
}

// ---------------------------------------------------------------------------
// LayerNorm (unbiased std, eps added to std), f32 in -> bf16 out
// ---------------------------------------------------------------------------
__global__ __launch_bounds__(256) void layernorm_k(
    const float* __restrict__ x, const float* __restrict__ sc,
    const float* __restrict__ sh, unsigned short* __restrict__ outp)
{
    const int row = blockIdx.x;
    const int tid = threadIdx.x;
    const float4 v = ((const float4*)(x + (size_t)row * EMB))[tid];
    float s  = v.x + v.y + v.z + v.w;
    float ss = v.x * v.x + v.y * v.y + v.z * v.z + v.w * v.w;
#pragma unroll
    for (int o = 32; o > 0; o >>= 1) {
        s  += __shfl_down(s, o);
        ss += __shfl_down(ss, o);
    }
    __shared__ float red[8];
    if ((tid & 63) == 0) { red[tid >> 6] = s; red[(tid >> 6) + 4] = ss; }
    __syncthreads();
    s  = red[0] + red[1] + red[2] + red[3];
    ss = red[4] + red[5] + red[6] + red[7];
    const float mean = s * (1.0f / EMB);
    const float var  = (ss - s * mean) * (1.0f / (EMB - 1));
    const float inv  = 1.0f / (sqrtf(var) + 1e-5f);
    const int c = tid << 2;
    ushort4 o4;
    o4.x = f2bf((v.x - mean) * inv * sc[c + 0] + sh[c + 0]);
    o4.y = f2bf((v.y - mean) * inv * sc[c + 1] + sh[c + 1]);
    o4.z = f2bf((v.z - mean) * inv * sc[c + 2] + sh[c + 2]);
    o4.w = f2bf((v.w - mean) * inv * sc[c + 3] + sh[c + 3]);
    ((ushort4*)(outp + (size_t)row * EMB))[tid] = o4;
}

// ---------------------------------------------------------------------------
// V transpose per head: qkv V-part [s][d] -> vt[b][h][d][s]
// ---------------------------------------------------------------------------
__global__ __launch_bounds__(256) void vtrans_k(
    const unsigned short* __restrict__ qkv, unsigned short* __restrict__ vt)
{
    __shared__ unsigned short T[64 * 64];
    const int tid = threadIdx.x;
    const int st = blockIdx.x, h = blockIdx.y, b = blockIdx.z;
    const size_t rowbase = (size_t)b * SEQ;
    const unsigned short* vsrc = qkv + (rowbase + (st << 6)) * 3072 + 2 * EMB + h * 64;
#pragma unroll
    for (int it = 0; it < 2; ++it) {
        const int s  = (it << 5) + (tid >> 3);
        const int d8 = tid & 7;
        uint4 w = *(const uint4*)(vsrc + (size_t)s * 3072 + (d8 << 3));
        *(uint4*)&T[(s << 6) + ((d8 ^ (s & 7)) << 3)] = w;
    }
    __syncthreads();
    unsigned short* vdst = vt + ((size_t)(b * NHEAD + h) << 6) * SEQ + (st << 6);
#pragma unroll
    for (int it = 0; it < 2; ++it) {
        const int d  = (it << 5) + (tid >> 3);
        const int s8 = tid & 7;
        unsigned short o8[8];
#pragma unroll
        for (int j = 0; j < 8; ++j) {
            const int s = (s8 << 3) + j;
            o8[j] = T[(s << 6) + (((d >> 3) ^ (s & 7)) << 3) + (d & 7)];
        }
        *(uint4*)(vdst + (size_t)d * SEQ + (s8 << 3)) = *(const uint4*)o8;
    }
}

// ---------------------------------------------------------------------------
// Causal flash attention, swapped-QK^T wave-local softmax.
// Block = 4 waves; wave owns 16 q-rows; KV tiles of 64; double-buffered async
// staging. Lane owns one q-row (q = lane&15); S^T/P^T live lane-local.
// 1-D grid 512 decoded so all 16 blocks of one (b,h) share an XCD.
// ---------------------------------------------------------------------------
__global__ __launch_bounds__(256) void attn_k(
    const unsigned short* __restrict__ qkv, const unsigned short* __restrict__ vt,
    unsigned short* __restrict__ ctx)
{
    __shared__ unsigned short Ks[2][64 * 64];
    __shared__ unsigned short Vts[2][64 * 64];
    __shared__ unsigned short Ps[4][16 * 64];
    const int tid  = threadIdx.x;
    const int lane = tid & 63;
    const int wid  = tid >> 6;
    const int q    = lane & 15;        // this lane's q-row within the wave tile
    const int lg   = lane >> 4;        // lane group 0..3

    // XCD-grouped decode: same (b,h) -> same id mod 8 -> same XCD L2
    const int id = blockIdx.x;                 // 0..511
    const int xcd = id & 7, i = id >> 3;       // i 0..63
    const int grp = ((i >> 4) << 3) + xcd;     // 0..31
    const int pairi = i & 15;
    const int h = grp & 15;
    const int b = grp >> 4;

    const size_t rowbase = (size_t)b * SEQ;
    const unsigned short* kbase = qkv + rowbase * 3072 + EMB + h * 64;       // + s*3072
    const unsigned short* vbase = vt + ((size_t)(b * NHEAD + h) << 6) * SEQ; // [d][s]

    auto stage = [&](int buf, int t) {
#pragma unroll
        for (int c = 0; c < 2; ++c) {
            const int idx = (wid << 10) + (c << 9) + (lane << 3);   // elem in [64*64]
            {   // K tile: [kv][d], swizzled 8-elem slots
                const int kv  = idx >> 6;
                const int d8s = ((idx >> 3) & 7) ^ (kv & 7);
                const unsigned short* g = kbase + (size_t)((t << 6) + kv) * 3072 + (d8s << 3);
                __builtin_amdgcn_global_load_lds(
                    (const __attribute__((address_space(1))) unsigned int*)g,
                    (__attribute__((address_space(3))) unsigned int*)&Ks[buf][idx], 16, 0, 0);
            }
            {   // V^T tile: [d][s], swizzled
                const int d   = idx >> 6;
                const int s8s = ((idx >> 3) & 7) ^ (d & 7);
                const unsigned short* g = vbase + (size_t)d * SEQ + (t << 6) + (s8s << 3);
                __builtin_amdgcn_global_load_lds(
                    (const __attribute__((address_space(1))) unsigned int*)g,
                    (__attribute__((address_space(3))) unsigned int*)&Vts[buf][idx], 16, 0, 0);
            }
        }
    };

    const f32x4 zero = {0.f, 0.f, 0.f, 0.f};
    const float QSC = 0.18033688011112042f;   // 0.125 * log2(e): exp2-domain scores

#pragma unroll 1
    for (int pass = 0; pass < 2; ++pass) {
        const int qt = pass ? (31 - pairi) : pairi;
        const int qrow0 = (qt << 6) + (wid << 4);
        const int qglob = qrow0 + q;

        bf16x8 qf[2];
        {
            const unsigned short* qp = qkv + (rowbase + qglob) * 3072 + h * 64;
            qf[0] = scale8(*(const bf16x8*)&qp[(lg << 3)], QSC);
            qf[1] = scale8(*(const bf16x8*)&qp[32 + (lg << 3)], QSC);
        }

        f32x4 accd[4];                 // O^T: d = dg*16 + lg*4 + r, col q
#pragma unroll
        for (int dg = 0; dg < 4; ++dg) accd[dg] = zero;
        float mrow = -__builtin_inff();
        float lrow = 0.f;

        stage(0, 0);
#pragma unroll 1
        for (int t = 0; t <= qt; ++t) {
            __syncthreads();                   // buf (t&1) ready; prev compute done
            if (t < qt) stage((t + 1) & 1, t + 1);
            const unsigned short* ks = Ks[t & 1];
            const unsigned short* vs = Vts[t & 1];

            // S^T = (K Q^T): rows kv, cols q. Lane holds kv = g*16+lg*4+r for its q.
            f32x4 sg[4];
#pragma unroll
            for (int g = 0; g < 4; ++g) {
                f32x4 sv = zero;
#pragma unroll
                for (int f = 0; f < 2; ++f) {
                    const int krow = (g << 4) + q;
                    const int cb   = (f << 5) + (lg << 3);
                    bf16x8 kf = *(const bf16x8*)&ks[(krow << 6) + (cb ^ ((krow & 7) << 3))];
                    sv = mfma16(kf, qf[f], sv);
                }
                sg[g] = sv;
            }
            if (t == qt) {
#pragma unroll
                for (int g = 0; g < 4; ++g) {
#pragma unroll
                    for (int r = 0; r < 4; ++r) {
                        const int kvg = (t << 6) + (g << 4) + (lg << 2) + r;
                        if (kvg > qglob) sg[g][r] = -__builtin_inff();
                    }
                }
            }

            // wave-local online softmax (exp2 domain)
            float mx = sg[0][0];
#pragma unroll
            for (int g = 0; g < 4; ++g)
#pragma unroll
                for (int r = 0; r < 4; ++r) mx = fmaxf(mx, sg[g][r]);
            mx = fmaxf(mx, __shfl_xor(mx, 16));
            mx = fmaxf(mx, __shfl_xor(mx, 32));
            if (__any(mx > mrow + 8.0f)) {     // defer-max: rescale only on growth
                const float mn = fmaxf(mrow, mx);
                const float so = exp2f(mrow - mn);
                mrow = mn;
                lrow *= so;
#pragma unroll
                for (int dg = 0; dg < 4; ++dg) accd[dg] *= so;
            }
            float rs = 0.f;
#pragma unroll
            for (int g = 0; g < 4; ++g)
#pragma unroll
                for (int r = 0; r < 4; ++r) {
                    const float pv = exp2f(sg[g][r] - mrow);
                    sg[g][r] = pv;
                    rs += pv;
                }
            rs += __shfl_xor(rs, 16);
            rs += __shfl_xor(rs, 32);
            lrow += rs;

            // P -> LDS: row-major [q][kv], (q&7) XOR-swizzled 8-elem slots
#pragma unroll
            for (int g = 0; g < 4; ++g) {
                uint2 w;
                w.x = pack2bf(sg[g][0], sg[g][1]);
                w.y = pack2bf(sg[g][2], sg[g][3]);
                const int e = ((g << 4) + (lg << 2)) ^ ((q & 7) << 3);
                *(uint2*)&Ps[wid][(q << 6) + e] = w;
            }

            // O^T += V^T P : A = V^T rows d, B = P rows q
            bf16x8 pa[2];
#pragma unroll
            for (int f = 0; f < 2; ++f) {
                const int e = ((f << 5) + (lg << 3)) ^ ((q & 7) << 3);
                pa[f] = *(const bf16x8*)&Ps[wid][(q << 6) + e];
            }
#pragma unroll
            for (int dg = 0; dg < 4; ++dg) {
#pragma unroll
                for (int f = 0; f < 2; ++f) {
                    const int vrow = (dg << 4) + q;
                    const int cb   = (f << 5) + (lg << 3);
                    bf16x8 vb = *(const bf16x8*)&vs[(vrow << 6) + (cb ^ ((vrow & 7) << 3))];
                    accd[dg] = mfma16(vb, pa[f], accd[dg]);
                }
            }
        }

        const float inv = 1.0f / lrow;
        unsigned short* cp = ctx + (rowbase + qglob) * EMB + h * 64 + (lg << 2);
#pragma unroll
        for (int dg = 0; dg < 4; ++dg) {
            uint2 w;
            w.x = pack2bf(accd[dg][0] * inv, accd[dg][1] * inv);
            w.y = pack2bf(accd[dg][2] * inv, accd[dg][3] * inv);
            *(uint2*)(cp + (dg << 4)) = w;
        }
        __syncthreads();   // protect LDS bufs before next pass's stage(0,0)
    }
}

// ---------------------------------------------------------------------------
// W[K][N] f32 -> Wt[N][K] bf16 (tiled transpose)
// ---------------------------------------------------------------------------
__global__ __launch_bounds__(256) void transpose_cvt(
    const float* __restrict__ W, unsigned short* __restrict__ Wt, int K, int N)
{
    __shared__ float tbuf[32][33];
    const int n0 = blockIdx.x << 5;
    const int k0 = blockIdx.y << 5;
    const int tx = threadIdx.x & 31;
    const int ty = threadIdx.x >> 5;   // 0..7
#pragma unroll
    for (int j = 0; j < 32; j += 8)
        tbuf[ty + j][tx] = W[(size_t)(k0 + ty + j) * N + n0 + tx];
    __syncthreads();
#pragma unroll
    for (int j = 0; j < 32; j += 8)
        Wt[(size_t)(n0 + ty + j) * K + k0 + tx] = f2bf(tbuf[tx][ty + j]);
}

__global__ void pack_bias(const float* __restrict__ bq, const float* __restrict__ bk,
                          const float* __restrict__ bv, float* __restrict__ o)
{
    const int i = blockIdx.x * 256 + threadIdx.x;
    o[i] = (i < 1024) ? bq[i] : (i < 2048) ? bk[i - 1024] : bv[i - 2048];
}

// ---------------------------------------------------------------------------
extern "C" void kernel_launch(void* const* d_in, const int* in_sizes, int n_in,
                              void* d_out, int out_size, void* d_ws, size_t ws_size,
                              hipStream_t stream)
{
    const float* x   = (const float*)d_in[0];
    const float* l1s = (const float*)d_in[1];
    const float* l1b = (const float*)d_in[2];
    const float* l2s = (const float*)d_in[3];
    const float* l2b = (const float*)d_in[4];
    const float* wq  = (const float*)d_in[5];
    const float* bq  = (const float*)d_in[6];
    const float* wk  = (const float*)d_in[7];
    const float* bk  = (const float*)d_in[8];
    const float* wv  = (const float*)d_in[9];
    const float* bv  = (const float*)d_in[10];
    const float* wo  = (const float*)d_in[11];
    const float* bo  = (const float*)d_in[12];
    const float* wfc = (const float*)d_in[13];
    const float* bfc = (const float*)d_in[14];
    const float* wpr = (const float*)d_in[15];
    const float* bpr = (const float*)d_in[16];

    unsigned short* WtQKV = (unsigned short*)d_ws;                    // [3072][1024]
    unsigned short* WtO   = WtQKV + (size_t)3072 * 1024;              // [1024][1024]
    unsigned short* WtFC  = WtO   + (size_t)1024 * 1024;              // [4096][1024]
    unsigned short* WtPR  = WtFC  + (size_t)4096 * 1024;              // [1024][4096]
    unsigned short* LN1   = WtPR  + (size_t)1024 * 4096;              // [4096][1024]
    unsigned short* QKV   = LN1   + (size_t)4096 * 1024;              // [4096][3072]
    unsigned short* CTX   = QKV   + (size_t)4096 * 3072;              // [4096][1024]
    unsigned short* LN2   = CTX   + (size_t)4096 * 1024;              // [4096][1024]
    unsigned short* Gb    = LN2   + (size_t)4096 * 1024;              // [4096][4096]
    float* H    = (float*)(Gb + (size_t)4096 * 4096);                 // [4096][1024] f32
    float* BQKV = H + (size_t)4096 * 1024;                            // [3072]
    // VT aliases Gb: VT only live between vtrans_k and attn_k; Gb written later.
    unsigned short* VT = Gb;                                          // [2*16][64][2048]

    dim3 blk(256);
    transpose_cvt<<<dim3(32, 32), blk, 0, stream>>>(wq, WtQKV, 1024, 1024);
    transpose_cvt<<<dim3(32, 32), blk, 0, stream>>>(wk, WtQKV + (size_t)1024 * 1024, 1024, 1024);
    transpose_cvt<<<dim3(32, 32), blk, 0, stream>>>(wv, WtQKV + (size_t)2048 * 1024, 1024, 1024);
    transpose_cvt<<<dim3(32, 32), blk, 0, stream>>>(wo, WtO, 1024, 1024);
    transpose_cvt<<<dim3(128, 32), blk, 0, stream>>>(wfc, WtFC, 1024, 4096);
    transpose_cvt<<<dim3(32, 128), blk, 0, stream>>>(wpr, WtPR, 4096, 1024);
    pack_bias<<<dim3(12), blk, 0, stream>>>(bq, bk, bv, BQKV);

    layernorm_k<<<dim3(4096), blk, 0, stream>>>(x, l1s, l1b, LN1);
    gemm_bt<0><<<dim3(24, 32), blk, 0, stream>>>(LN1, WtQKV, BQKV, QKV, 4096, 3072, 1024);
    vtrans_k<<<dim3(32, NHEAD, 2), blk, 0, stream>>>(QKV, VT);
    attn_k<<<dim3(512), blk, 0, stream>>>(QKV, VT, CTX);
    // H = CTX @ WoT + bo + x   (BN=64 tile, 512 blocks)
    gemm_bt_n64<<<dim3(16, 32), blk, 0, stream>>>(CTX, WtO, bo, x, H, 4096, 1024, 1024);
    layernorm_k<<<dim3(4096), blk, 0, stream>>>(H, l2s, l2b, LN2);
    gemm_bt<1><<<dim3(32, 32), blk, 0, stream>>>(LN2, WtFC, bfc, Gb, 4096, 4096, 1024);
    // d_out = Gb @ WprT + bpr + H   (BN=64 tile, 512 blocks)
    gemm_bt_n64<<<dim3(16, 32), blk, 0, stream>>>(Gb, WtPR, bpr, H, (float*)d_out, 4096, 1024, 4096);
}

// Round 8
// 376.732 us; speedup vs baseline: 1.3758x; 1.0432x over previous
//
#include <hip/hip_runtime.h>
#include <hip/hip_bf16.h>

typedef float f32x4 __attribute__((ext_vector_type(4)));
typedef __bf16 bf16x8 __attribute__((ext_vector_type(8)));

#define EMB 1024
#define FFD 4096
#define NHEAD 16
#define HD 64
#define SEQ 2048
#define MROWS 4096

__device__ __forceinline__ unsigned short f2bf(float f) {
    unsigned int x = __builtin_bit_cast(unsigned int, f);
    x += 0x7fffu + ((x >> 16) & 1u);
    return (unsigned short)(x >> 16);
}

__device__ __forceinline__ unsigned int pack2bf(float a, float b) {
    return (unsigned int)f2bf(a) | ((unsigned int)f2bf(b) << 16);
}

__device__ __forceinline__ f32x4 mfma16(bf16x8 a, bf16x8 b, f32x4 c) {
    return __builtin_amdgcn_mfma_f32_16x16x32_bf16(a, b, c, 0, 0, 0);
}

__device__ __forceinline__ bf16x8 scale8(bf16x8 v, float s) {
    bf16x8 o;
#pragma unroll
    for (int i = 0; i < 8; ++i) o[i] = (__bf16)((float)v[i] * s);
    return o;
}

__device__ __forceinline__ float gelu_f(float x) {
    float u = 0.7978845608028654f * (x + 0.044715f * x * x * x);
    float e = __expf(2.0f * u);
    float th = 1.0f - 2.0f / (e + 1.0f);   // tanh(u), safe at +-inf
    return 0.5f * x * (1.0f + th);
}

// XCD-grouping remap: blocks sharing `by` (A-panel) land on the same XCD.
__device__ __forceinline__ void xcd_remap(int& bx, int& by) {
    const int nbx = gridDim.x;
    int id = blockIdx.x + nbx * blockIdx.y;
    int xcd = id & 7, i = id >> 3;
    by = (i / nbx) * 8 + xcd;
    bx = i % nbx;
}

// ---------------------------------------------------------------------------
// GEMM: C[M,N] = A[M,K](bf16) * Bt[N,K](bf16)^T, 128x128 tile, BK=32,
// global_load_lds staging, double buffer, XOR-swizzled LDS slots.
// EPI: 0 = +bias -> bf16 ; 1 = +bias,gelu -> bf16
// ---------------------------------------------------------------------------
template <int EPI>
__global__ __launch_bounds__(256) void gemm_bt(
    const unsigned short* __restrict__ A, const unsigned short* __restrict__ Bt,
    const float* __restrict__ bias,
    void* __restrict__ outp, int M, int N, int K)
{
    __shared__ unsigned short As[2][128 * 32];
    __shared__ unsigned short Bs[2][128 * 32];
    const int tid  = threadIdx.x;
    const int lane = tid & 63;
    const int wid  = tid >> 6;
    int bx, by; xcd_remap(bx, by);
    const int brow = by << 7;
    const int bcol = bx << 7;
    const int wr = wid >> 1, wc = wid & 1;

    f32x4 acc[4][4];
    const f32x4 zero = {0.f, 0.f, 0.f, 0.f};
#pragma unroll
    for (int m = 0; m < 4; ++m)
#pragma unroll
        for (int n = 0; n < 4; ++n) acc[m][n] = zero;

    const int nk = K >> 5;

    auto stage = [&](int buf, int k0) {
#pragma unroll
        for (int c = 0; c < 2; ++c) {
            int idx = (wid << 10) + (c << 9) + (lane << 3);     // linear elem in [128*32]
            int row = idx >> 5;
            int c8s = (idx >> 3) & 3;
            int c8g = c8s ^ ((row >> 1) & 3);                   // inverse-swizzled source
            const unsigned short* ga = A  + (size_t)(brow + row) * K + k0 + (c8g << 3);
            const unsigned short* gb = Bt + (size_t)(bcol + row) * K + k0 + (c8g << 3);
            __builtin_amdgcn_global_load_lds(
                (const __attribute__((address_space(1))) unsigned int*)ga,
                (__attribute__((address_space(3))) unsigned int*)&As[buf][idx], 16, 0, 0);
            __builtin_amdgcn_global_load_lds(
                (const __attribute__((address_space(1))) unsigned int*)gb,
                (__attribute__((address_space(3))) unsigned int*)&Bs[buf][idx], 16, 0, 0);
        }
    };

    stage(0, 0);
    for (int kt = 0; kt < nk; ++kt) {
        __syncthreads();                       // buf (kt&1) ready (barrier drains vmcnt)
        if (kt + 1 < nk) stage((kt + 1) & 1, (kt + 1) << 5);
        const unsigned short* as = As[kt & 1];
        const unsigned short* bs = Bs[kt & 1];
        const int kg = lane >> 4;
        bf16x8 afr[4], bfr[4];
#pragma unroll
        for (int m = 0; m < 4; ++m) {
            int row = (wr << 6) + (m << 4) + (lane & 15);
            int c8  = kg ^ ((row >> 1) & 3);
            afr[m] = *(const bf16x8*)&as[(row << 5) + (c8 << 3)];
        }
#pragma unroll
        for (int n = 0; n < 4; ++n) {
            int row = (wc << 6) + (n << 4) + (lane & 15);
            int c8  = kg ^ ((row >> 1) & 3);
            bfr[n] = *(const bf16x8*)&bs[(row << 5) + (c8 << 3)];
        }
#pragma unroll
        for (int m = 0; m < 4; ++m)
#pragma unroll
            for (int n = 0; n < 4; ++n)
                acc[m][n] = mfma16(afr[m], bfr[n], acc[m][n]);
        __syncthreads();
    }

#pragma unroll
    for (int m = 0; m < 4; ++m) {
#pragma unroll
        for (int n = 0; n < 4; ++n) {
            const int col = bcol + (wc << 6) + (n << 4) + (lane & 15);
            const float bv = bias[col];
#pragma unroll
            for (int r = 0; r < 4; ++r) {
                const int row = brow + (wr << 6) + (m << 4) + ((lane >> 4) << 2) + r;
                float v = acc[m][n][r] + bv;
                if (EPI == 1) v = gelu_f(v);
                ((unsigned short*)outp)[(size_t)row * N + col] = f2bf(v);
            }
        }
    }
}

// ---------------------------------------------------------------------------
// Narrow-N GEMM: BM=128, BN=64, BK=64. 4 waves, each 32 rows x 64 cols.
// 16 MFMA per barrier pair (2x the BK=32 version) to amortize barrier drain.
// LDS [row][64] with 8-slot XOR swizzle (slot ^= row&7): residual 2-way = free.
// Deterministic single-write epilogue: out = A*Bt^T + bias + resid (f32).
// ---------------------------------------------------------------------------
__global__ __launch_bounds__(256) void gemm_bt_n64(
    const unsigned short* __restrict__ A, const unsigned short* __restrict__ Bt,
    const float* __restrict__ bias, const float* __restrict__ resid,
    float* __restrict__ outp, int M, int N, int K)
{
    __shared__ unsigned short As[2][128 * 64];
    __shared__ unsigned short Bs[2][64 * 64];
    const int tid  = threadIdx.x;
    const int lane = tid & 63;
    const int wid  = tid >> 6;
    int bx, by; xcd_remap(bx, by);
    const int brow = by << 7;
    const int bcol = bx << 6;

    f32x4 acc[2][4];
    const f32x4 zero = {0.f, 0.f, 0.f, 0.f};
#pragma unroll
    for (int m = 0; m < 2; ++m)
#pragma unroll
        for (int n = 0; n < 4; ++n) acc[m][n] = zero;

    const int nk = K >> 6;

    auto stage = [&](int buf, int k0) {
#pragma unroll
        for (int c = 0; c < 4; ++c) {           // A tile: 128*64 elems, 4 rounds
            int idx = (c << 11) + (tid << 3);
            int row = idx >> 6;
            int c8g = ((idx >> 3) & 7) ^ (row & 7);
            const unsigned short* ga = A + (size_t)(brow + row) * K + k0 + (c8g << 3);
            __builtin_amdgcn_global_load_lds(
                (const __attribute__((address_space(1))) unsigned int*)ga,
                (__attribute__((address_space(3))) unsigned int*)&As[buf][idx], 16, 0, 0);
        }
#pragma unroll
        for (int c = 0; c < 2; ++c) {           // B tile: 64*64 elems, 2 rounds
            int idx = (c << 11) + (tid << 3);
            int row = idx >> 6;
            int c8g = ((idx >> 3) & 7) ^ (row & 7);
            const unsigned short* gb = Bt + (size_t)(bcol + row) * K + k0 + (c8g << 3);
            __builtin_amdgcn_global_load_lds(
                (const __attribute__((address_space(1))) unsigned int*)gb,
                (__attribute__((address_space(3))) unsigned int*)&Bs[buf][idx], 16, 0, 0);
        }
    };

    stage(0, 0);
    for (int kt = 0; kt < nk; ++kt) {
        __syncthreads();
        if (kt + 1 < nk) stage((kt + 1) & 1, (kt + 1) << 6);
        const unsigned short* as = As[kt & 1];
        const unsigned short* bs = Bs[kt & 1];
        const int kg = lane >> 4;
#pragma unroll
        for (int f = 0; f < 2; ++f) {
            bf16x8 afr[2], bfr[4];
#pragma unroll
            for (int m = 0; m < 2; ++m) {
                int row = (wid << 5) + (m << 4) + (lane & 15);
                int c8  = ((f << 2) + kg) ^ (row & 7);
                afr[m] = *(const bf16x8*)&as[(row << 6) + (c8 << 3)];
            }
#pragma unroll
            for (int n = 0; n < 4; ++n) {
                int row = (n << 4) + (lane & 15);
                int c8  = ((f << 2) + kg) ^ (row & 7);
                bfr[n] = *(const bf16x8*)&bs[(row << 6) + (c8 << 3)];
            }
#pragma unroll
            for (int m = 0; m < 2; ++m)
#pragma unroll
                for (int n = 0; n < 4; ++n)
                    acc[m][n] = mfma16(afr[m], bfr[n], acc[m][n]);
        }
        __syncthreads();
    }

#pragma unroll
    for (int m = 0; m < 2; ++m)
#pragma unroll
        for (int n = 0; n < 4; ++n) {
            const int col = bcol + (n << 4) + (lane & 15);
            const float bv = bias[col];
#pragma unroll
            for (int r = 0; r < 4; ++r) {
                const int row = brow + (wid << 5) + (m << 4) + ((lane >> 4) << 2) + r;
                outp[(size_t)row * N + col] =
                    acc[m][n][r] + bv + resid[(size_t)row * N + col];
            }
        }
}

// ---------------------------------------------------------------------------
// LayerNorm (unbiased std, eps added to std), f32 in -> bf16 out
// ---------------------------------------------------------------------------
__global__ __launch_bounds__(256) void layernorm_k(
    const float* __restrict__ x, const float* __restrict__ sc,
    const float* __restrict__ sh, unsigned short* __restrict__ outp)
{
    const int row = blockIdx.x;
    const int tid = threadIdx.x;
    const float4 v = ((const float4*)(x + (size_t)row * EMB))[tid];
    float s  = v.x + v.y + v.z + v.w;
    float ss = v.x * v.x + v.y * v.y + v.z * v.z + v.w * v.w;
#pragma unroll
    for (int o = 32; o > 0; o >>= 1) {
        s  += __shfl_down(s, o);
        ss += __shfl_down(ss, o);
    }
    __shared__ float red[8];
    if ((tid & 63) == 0) { red[tid >> 6] = s; red[(tid >> 6) + 4] = ss; }
    __syncthreads();
    s  = red[0] + red[1] + red[2] + red[3];
    ss = red[4] + red[5] + red[6] + red[7];
    const float mean = s * (1.0f / EMB);
    const float var  = (ss - s * mean) * (1.0f / (EMB - 1));
    const float inv  = 1.0f / (sqrtf(var) + 1e-5f);
    const int c = tid << 2;
    ushort4 o4;
    o4.x = f2bf((v.x - mean) * inv * sc[c + 0] + sh[c + 0]);
    o4.y = f2bf((v.y - mean) * inv * sc[c + 1] + sh[c + 1]);
    o4.z = f2bf((v.z - mean) * inv * sc[c + 2] + sh[c + 2]);
    o4.w = f2bf((v.w - mean) * inv * sc[c + 3] + sh[c + 3]);
    ((ushort4*)(outp + (size_t)row * EMB))[tid] = o4;
}

// ---------------------------------------------------------------------------
// V transpose per head: qkv V-part [s][d] -> vt[b][h][d][s]
// ---------------------------------------------------------------------------
__global__ __launch_bounds__(256) void vtrans_k(
    const unsigned short* __restrict__ qkv, unsigned short* __restrict__ vt)
{
    __shared__ unsigned short T[64 * 64];
    const int tid = threadIdx.x;
    const int st = blockIdx.x, h = blockIdx.y, b = blockIdx.z;
    const size_t rowbase = (size_t)b * SEQ;
    const unsigned short* vsrc = qkv + (rowbase + (st << 6)) * 3072 + 2 * EMB + h * 64;
#pragma unroll
    for (int it = 0; it < 2; ++it) {
        const int s  = (it << 5) + (tid >> 3);
        const int d8 = tid & 7;
        uint4 w = *(const uint4*)(vsrc + (size_t)s * 3072 + (d8 << 3));
        *(uint4*)&T[(s << 6) + ((d8 ^ (s & 7)) << 3)] = w;
    }
    __syncthreads();
    unsigned short* vdst = vt + ((size_t)(b * NHEAD + h) << 6) * SEQ + (st << 6);
#pragma unroll
    for (int it = 0; it < 2; ++it) {
        const int d  = (it << 5) + (tid >> 3);
        const int s8 = tid & 7;
        unsigned short o8[8];
#pragma unroll
        for (int j = 0; j < 8; ++j) {
            const int s = (s8 << 3) + j;
            o8[j] = T[(s << 6) + (((d >> 3) ^ (s & 7)) << 3) + (d & 7)];
        }
        *(uint4*)(vdst + (size_t)d * SEQ + (s8 << 3)) = *(const uint4*)o8;
    }
}

// ---------------------------------------------------------------------------
// Causal flash attention, swapped-QK^T wave-local softmax.
// Block = 4 waves; wave owns 16 q-rows; KV tiles of 64; double-buffered async
// staging. Lane owns one q-row (q = lane&15); S^T/P^T live lane-local.
// 1-D grid 512 decoded so all 16 blocks of one (b,h) share an XCD.
// ---------------------------------------------------------------------------
__global__ __launch_bounds__(256) void attn_k(
    const unsigned short* __restrict__ qkv, const unsigned short* __restrict__ vt,
    unsigned short* __restrict__ ctx)
{
    __shared__ unsigned short Ks[2][64 * 64];
    __shared__ unsigned short Vts[2][64 * 64];
    __shared__ unsigned short Ps[4][16 * 64];
    const int tid  = threadIdx.x;
    const int lane = tid & 63;
    const int wid  = tid >> 6;
    const int q    = lane & 15;        // this lane's q-row within the wave tile
    const int lg   = lane >> 4;        // lane group 0..3

    // XCD-grouped decode: same (b,h) -> same id mod 8 -> same XCD L2
    const int id = blockIdx.x;                 // 0..511
    const int xcd = id & 7, i = id >> 3;       // i 0..63
    const int grp = ((i >> 4) << 3) + xcd;     // 0..31
    const int pairi = i & 15;
    const int h = grp & 15;
    const int b = grp >> 4;

    const size_t rowbase = (size_t)b * SEQ;
    const unsigned short* kbase = qkv + rowbase * 3072 + EMB + h * 64;       // + s*3072
    const unsigned short* vbase = vt + ((size_t)(b * NHEAD + h) << 6) * SEQ; // [d][s]

    auto stage = [&](int buf, int t) {
#pragma unroll
        for (int c = 0; c < 2; ++c) {
            const int idx = (wid << 10) + (c << 9) + (lane << 3);   // elem in [64*64]
            {   // K tile: [kv][d], swizzled 8-elem slots
                const int kv  = idx >> 6;
                const int d8s = ((idx >> 3) & 7) ^ (kv & 7);
                const unsigned short* g = kbase + (size_t)((t << 6) + kv) * 3072 + (d8s << 3);
                __builtin_amdgcn_global_load_lds(
                    (const __attribute__((address_space(1))) unsigned int*)g,
                    (__attribute__((address_space(3))) unsigned int*)&Ks[buf][idx], 16, 0, 0);
            }
            {   // V^T tile: [d][s], swizzled
                const int d   = idx >> 6;
                const int s8s = ((idx >> 3) & 7) ^ (d & 7);
                const unsigned short* g = vbase + (size_t)d * SEQ + (t << 6) + (s8s << 3);
                __builtin_amdgcn_global_load_lds(
                    (const __attribute__((address_space(1))) unsigned int*)g,
                    (__attribute__((address_space(3))) unsigned int*)&Vts[buf][idx], 16, 0, 0);
            }
        }
    };

    const f32x4 zero = {0.f, 0.f, 0.f, 0.f};
    const float QSC = 0.18033688011112042f;   // 0.125 * log2(e): exp2-domain scores

#pragma unroll 1
    for (int pass = 0; pass < 2; ++pass) {
        const int qt = pass ? (31 - pairi) : pairi;
        const int qrow0 = (qt << 6) + (wid << 4);
        const int qglob = qrow0 + q;

        bf16x8 qf[2];
        {
            const unsigned short* qp = qkv + (rowbase + qglob) * 3072 + h * 64;
            qf[0] = scale8(*(const bf16x8*)&qp[(lg << 3)], QSC);
            qf[1] = scale8(*(const bf16x8*)&qp[32 + (lg << 3)], QSC);
        }

        f32x4 accd[4];                 // O^T: d = dg*16 + lg*4 + r, col q
#pragma unroll
        for (int dg = 0; dg < 4; ++dg) accd[dg] = zero;
        float mrow = -__builtin_inff();
        float lrow = 0.f;

        stage(0, 0);
#pragma unroll 1
        for (int t = 0; t <= qt; ++t) {
            __syncthreads();                   // buf (t&1) ready; prev compute done
            if (t < qt) stage((t + 1) & 1, t + 1);
            const unsigned short* ks = Ks[t & 1];
            const unsigned short* vs = Vts[t & 1];

            // S^T = (K Q^T): rows kv, cols q. Lane holds kv = g*16+lg*4+r for its q.
            f32x4 sg[4];
#pragma unroll
            for (int g = 0; g < 4; ++g) {
                f32x4 sv = zero;
#pragma unroll
                for (int f = 0; f < 2; ++f) {
                    const int krow = (g << 4) + q;
                    const int cb   = (f << 5) + (lg << 3);
                    bf16x8 kf = *(const bf16x8*)&ks[(krow << 6) + (cb ^ ((krow & 7) << 3))];
                    sv = mfma16(kf, qf[f], sv);
                }
                sg[g] = sv;
            }
            if (t == qt) {
#pragma unroll
                for (int g = 0; g < 4; ++g) {
#pragma unroll
                    for (int r = 0; r < 4; ++r) {
                        const int kvg = (t << 6) + (g << 4) + (lg << 2) + r;
                        if (kvg > qglob) sg[g][r] = -__builtin_inff();
                    }
                }
            }

            // wave-local online softmax (exp2 domain)
            float mx = sg[0][0];
#pragma unroll
            for (int g = 0; g < 4; ++g)
#pragma unroll
                for (int r = 0; r < 4; ++r) mx = fmaxf(mx, sg[g][r]);
            mx = fmaxf(mx, __shfl_xor(mx, 16));
            mx = fmaxf(mx, __shfl_xor(mx, 32));
            if (__any(mx > mrow + 8.0f)) {     // defer-max: rescale only on growth
                const float mn = fmaxf(mrow, mx);
                const float so = exp2f(mrow - mn);
                mrow = mn;
                lrow *= so;
#pragma unroll
                for (int dg = 0; dg < 4; ++dg) accd[dg] *= so;
            }
            float rs = 0.f;
#pragma unroll
            for (int g = 0; g < 4; ++g)
#pragma unroll
                for (int r = 0; r < 4; ++r) {
                    const float pv = exp2f(sg[g][r] - mrow);
                    sg[g][r] = pv;
                    rs += pv;
                }
            rs += __shfl_xor(rs, 16);
            rs += __shfl_xor(rs, 32);
            lrow += rs;

            // P -> LDS: row-major [q][kv], (q&7) XOR-swizzled 8-elem slots
#pragma unroll
            for (int g = 0; g < 4; ++g) {
                uint2 w;
                w.x = pack2bf(sg[g][0], sg[g][1]);
                w.y = pack2bf(sg[g][2], sg[g][3]);
                const int e = ((g << 4) + (lg << 2)) ^ ((q & 7) << 3);
                *(uint2*)&Ps[wid][(q << 6) + e] = w;
            }

            // O^T += V^T P : A = V^T rows d, B = P rows q
            bf16x8 pa[2];
#pragma unroll
            for (int f = 0; f < 2; ++f) {
                const int e = ((f << 5) + (lg << 3)) ^ ((q & 7) << 3);
                pa[f] = *(const bf16x8*)&Ps[wid][(q << 6) + e];
            }
#pragma unroll
            for (int dg = 0; dg < 4; ++dg) {
#pragma unroll
                for (int f = 0; f < 2; ++f) {
                    const int vrow = (dg << 4) + q;
                    const int cb   = (f << 5) + (lg << 3);
                    bf16x8 vb = *(const bf16x8*)&vs[(vrow << 6) + (cb ^ ((vrow & 7) << 3))];
                    accd[dg] = mfma16(vb, pa[f], accd[dg]);
                }
            }
        }

        const float inv = 1.0f / lrow;
        unsigned short* cp = ctx + (rowbase + qglob) * EMB + h * 64 + (lg << 2);
#pragma unroll
        for (int dg = 0; dg < 4; ++dg) {
            uint2 w;
            w.x = pack2bf(accd[dg][0] * inv, accd[dg][1] * inv);
            w.y = pack2bf(accd[dg][2] * inv, accd[dg][3] * inv);
            *(uint2*)(cp + (dg << 4)) = w;
        }
        __syncthreads();   // protect LDS bufs before next pass's stage(0,0)
    }
}

// ---------------------------------------------------------------------------
// W[K][N] f32 -> Wt[N][K] bf16 (tiled transpose)
// ---------------------------------------------------------------------------
__global__ __launch_bounds__(256) void transpose_cvt(
    const float* __restrict__ W, unsigned short* __restrict__ Wt, int K, int N)
{
    __shared__ float tbuf[32][33];
    const int n0 = blockIdx.x << 5;
    const int k0 = blockIdx.y << 5;
    const int tx = threadIdx.x & 31;
    const int ty = threadIdx.x >> 5;   // 0..7
#pragma unroll
    for (int j = 0; j < 32; j += 8)
        tbuf[ty + j][tx] = W[(size_t)(k0 + ty + j) * N + n0 + tx];
    __syncthreads();
#pragma unroll
    for (int j = 0; j < 32; j += 8)
        Wt[(size_t)(n0 + ty + j) * K + k0 + tx] = f2bf(tbuf[tx][ty + j]);
}

__global__ void pack_bias(const float* __restrict__ bq, const float* __restrict__ bk,
                          const float* __restrict__ bv, float* __restrict__ o)
{
    const int i = blockIdx.x * 256 + threadIdx.x;
    o[i] = (i < 1024) ? bq[i] : (i < 2048) ? bk[i - 1024] : bv[i - 2048];
}

// ---------------------------------------------------------------------------
extern "C" void kernel_launch(void* const* d_in, const int* in_sizes, int n_in,
                              void* d_out, int out_size, void* d_ws, size_t ws_size,
                              hipStream_t stream)
{
    const float* x   = (const float*)d_in[0];
    const float* l1s = (const float*)d_in[1];
    const float* l1b = (const float*)d_in[2];
    const float* l2s = (const float*)d_in[3];
    const float* l2b = (const float*)d_in[4];
    const float* wq  = (const float*)d_in[5];
    const float* bq  = (const float*)d_in[6];
    const float* wk  = (const float*)d_in[7];
    const float* bk  = (const float*)d_in[8];
    const float* wv  = (const float*)d_in[9];
    const float* bv  = (const float*)d_in[10];
    const float* wo  = (const float*)d_in[11];
    const float* bo  = (const float*)d_in[12];
    const float* wfc = (const float*)d_in[13];
    const float* bfc = (const float*)d_in[14];
    const float* wpr = (const float*)d_in[15];
    const float* bpr = (const float*)d_in[16];

    unsigned short* WtQKV = (unsigned short*)d_ws;                    // [3072][1024]
    unsigned short* WtO   = WtQKV + (size_t)3072 * 1024;              // [1024][1024]
    unsigned short* WtFC  = WtO   + (size_t)1024 * 1024;              // [4096][1024]
    unsigned short* WtPR  = WtFC  + (size_t)4096 * 1024;              // [1024][4096]
    unsigned short* LN1   = WtPR  + (size_t)1024 * 4096;              // [4096][1024]
    unsigned short* QKV   = LN1   + (size_t)4096 * 1024;              // [4096][3072]
    unsigned short* CTX   = QKV   + (size_t)4096 * 3072;              // [4096][1024]
    unsigned short* LN2   = CTX   + (size_t)4096 * 1024;              // [4096][1024]
    unsigned short* Gb    = LN2   + (size_t)4096 * 1024;              // [4096][4096]
    float* H    = (float*)(Gb + (size_t)4096 * 4096);                 // [4096][1024] f32
    float* BQKV = H + (size_t)4096 * 1024;                            // [3072]
    // VT aliases Gb: VT only live between vtrans_k and attn_k; Gb written later.
    unsigned short* VT = Gb;                                          // [2*16][64][2048]

    dim3 blk(256);
    transpose_cvt<<<dim3(32, 32), blk, 0, stream>>>(wq, WtQKV, 1024, 1024);
    transpose_cvt<<<dim3(32, 32), blk, 0, stream>>>(wk, WtQKV + (size_t)1024 * 1024, 1024, 1024);
    transpose_cvt<<<dim3(32, 32), blk, 0, stream>>>(wv, WtQKV + (size_t)2048 * 1024, 1024, 1024);
    transpose_cvt<<<dim3(32, 32), blk, 0, stream>>>(wo, WtO, 1024, 1024);
    transpose_cvt<<<dim3(128, 32), blk, 0, stream>>>(wfc, WtFC, 1024, 4096);
    transpose_cvt<<<dim3(32, 128), blk, 0, stream>>>(wpr, WtPR, 4096, 1024);
    pack_bias<<<dim3(12), blk, 0, stream>>>(bq, bk, bv, BQKV);

    layernorm_k<<<dim3(4096), blk, 0, stream>>>(x, l1s, l1b, LN1);
    gemm_bt<0><<<dim3(24, 32), blk, 0, stream>>>(LN1, WtQKV, BQKV, QKV, 4096, 3072, 1024);
    vtrans_k<<<dim3(32, NHEAD, 2), blk, 0, stream>>>(QKV, VT);
    attn_k<<<dim3(512), blk, 0, stream>>>(QKV, VT, CTX);
    // H = CTX @ WoT + bo + x   (BN=64/BK=64 tile, 512 blocks)
    gemm_bt_n64<<<dim3(16, 32), blk, 0, stream>>>(CTX, WtO, bo, x, H, 4096, 1024, 1024);
    layernorm_k<<<dim3(4096), blk, 0, stream>>>(H, l2s, l2b, LN2);
    gemm_bt<1><<<dim3(32, 32), blk, 0, stream>>>(LN2, WtFC, bfc, Gb, 4096, 4096, 1024);
    // d_out = Gb @ WprT + bpr + H   (BN=64/BK=64 tile, 512 blocks)
    gemm_bt_n64<<<dim3(16, 32), blk, 0, stream>>>(Gb, WtPR, bpr, H, (float*)d_out, 4096, 1024, 4096);
}

// Round 9
// 375.028 us; speedup vs baseline: 1.3821x; 1.0045x over previous
//
#include <hip/hip_runtime.h>
#include <hip/hip_bf16.h>

typedef float f32x4 __attribute__((ext_vector_type(4)));
typedef __bf16 bf16x8 __attribute__((ext_vector_type(8)));

#define EMB 1024
#define FFD 4096
#define NHEAD 16
#define HD 64
#define SEQ 2048
#define MROWS 4096

// Native cast -> compiler emits packed v_cvt_pk_bf16_f32 (RNE), far fewer VALU
// ops than a manual bit-twiddle (m240: scalar casts compile well).
__device__ __forceinline__ unsigned short f2bf(float f) {
    return __builtin_bit_cast(unsigned short, (__bf16)f);
}

__device__ __forceinline__ unsigned int pack2bf(float a, float b) {
    unsigned short lo = __builtin_bit_cast(unsigned short, (__bf16)a);
    unsigned short hi = __builtin_bit_cast(unsigned short, (__bf16)b);
    return (unsigned int)lo | ((unsigned int)hi << 16);
}

__device__ __forceinline__ f32x4 mfma16(bf16x8 a, bf16x8 b, f32x4 c) {
    return __builtin_amdgcn_mfma_f32_16x16x32_bf16(a, b, c, 0, 0, 0);
}

__device__ __forceinline__ float gelu_f(float x) {
    float u = 0.7978845608028654f * (x + 0.044715f * x * x * x);
    float e = __expf(2.0f * u);
    float th = 1.0f - 2.0f / (e + 1.0f);   // tanh(u), safe at +-inf
    return 0.5f * x * (1.0f + th);
}

// XCD-grouping remap: blocks sharing `by` (A-panel) land on the same XCD.
__device__ __forceinline__ void xcd_remap(int& bx, int& by) {
    const int nbx = gridDim.x;
    int id = blockIdx.x + nbx * blockIdx.y;
    int xcd = id & 7, i = id >> 3;
    by = (i / nbx) * 8 + xcd;
    bx = i % nbx;
}

// ---------------------------------------------------------------------------
// GEMM: C[M,N] = A[M,K](bf16) * Bt[N,K](bf16)^T, 128x128 tile, BK=32,
// global_load_lds staging, double buffer, XOR-swizzled LDS slots.
// EPI: 0 = +bias -> bf16 ; 1 = +bias,gelu -> bf16
// ---------------------------------------------------------------------------
template <int EPI>
__global__ __launch_bounds__(256) void gemm_bt(
    const unsigned short* __restrict__ A, const unsigned short* __restrict__ Bt,
    const float* __restrict__ bias,
    void* __restrict__ outp, int M, int N, int K)
{
    __shared__ unsigned short As[2][128 * 32];
    __shared__ unsigned short Bs[2][128 * 32];
    const int tid  = threadIdx.x;
    const int lane = tid & 63;
    const int wid  = tid >> 6;
    int bx, by; xcd_remap(bx, by);
    const int brow = by << 7;
    const int bcol = bx << 7;
    const int wr = wid >> 1, wc = wid & 1;

    f32x4 acc[4][4];
    const f32x4 zero = {0.f, 0.f, 0.f, 0.f};
#pragma unroll
    for (int m = 0; m < 4; ++m)
#pragma unroll
        for (int n = 0; n < 4; ++n) acc[m][n] = zero;

    const int nk = K >> 5;

    auto stage = [&](int buf, int k0) {
#pragma unroll
        for (int c = 0; c < 2; ++c) {
            int idx = (wid << 10) + (c << 9) + (lane << 3);     // linear elem in [128*32]
            int row = idx >> 5;
            int c8s = (idx >> 3) & 3;
            int c8g = c8s ^ ((row >> 1) & 3);                   // inverse-swizzled source
            const unsigned short* ga = A  + (size_t)(brow + row) * K + k0 + (c8g << 3);
            const unsigned short* gb = Bt + (size_t)(bcol + row) * K + k0 + (c8g << 3);
            __builtin_amdgcn_global_load_lds(
                (const __attribute__((address_space(1))) unsigned int*)ga,
                (__attribute__((address_space(3))) unsigned int*)&As[buf][idx], 16, 0, 0);
            __builtin_amdgcn_global_load_lds(
                (const __attribute__((address_space(1))) unsigned int*)gb,
                (__attribute__((address_space(3))) unsigned int*)&Bs[buf][idx], 16, 0, 0);
        }
    };

    stage(0, 0);
    for (int kt = 0; kt < nk; ++kt) {
        __syncthreads();                       // buf (kt&1) ready (barrier drains vmcnt)
        if (kt + 1 < nk) stage((kt + 1) & 1, (kt + 1) << 5);
        const unsigned short* as = As[kt & 1];
        const unsigned short* bs = Bs[kt & 1];
        const int kg = lane >> 4;
        bf16x8 afr[4], bfr[4];
#pragma unroll
        for (int m = 0; m < 4; ++m) {
            int row = (wr << 6) + (m << 4) + (lane & 15);
            int c8  = kg ^ ((row >> 1) & 3);
            afr[m] = *(const bf16x8*)&as[(row << 5) + (c8 << 3)];
        }
#pragma unroll
        for (int n = 0; n < 4; ++n) {
            int row = (wc << 6) + (n << 4) + (lane & 15);
            int c8  = kg ^ ((row >> 1) & 3);
            bfr[n] = *(const bf16x8*)&bs[(row << 5) + (c8 << 3)];
        }
        __builtin_amdgcn_s_setprio(1);
#pragma unroll
        for (int m = 0; m < 4; ++m)
#pragma unroll
            for (int n = 0; n < 4; ++n)
                acc[m][n] = mfma16(afr[m], bfr[n], acc[m][n]);
        __builtin_amdgcn_s_setprio(0);
        __syncthreads();
    }

#pragma unroll
    for (int m = 0; m < 4; ++m) {
#pragma unroll
        for (int n = 0; n < 4; ++n) {
            const int col = bcol + (wc << 6) + (n << 4) + (lane & 15);
            const float bv = bias[col];
#pragma unroll
            for (int r = 0; r < 4; ++r) {
                const int row = brow + (wr << 6) + (m << 4) + ((lane >> 4) << 2) + r;
                float v = acc[m][n][r] + bv;
                if (EPI == 1) v = gelu_f(v);
                ((unsigned short*)outp)[(size_t)row * N + col] = f2bf(v);
            }
        }
    }
}

// ---------------------------------------------------------------------------
// Narrow-N GEMM: BM=128, BN=64, BK=64. 4 waves, each 32 rows x 64 cols.
// 16 MFMA per barrier pair. LDS [row][64] with 8-slot XOR swizzle.
// Deterministic single-write epilogue: out = A*Bt^T + bias + resid (f32).
// ---------------------------------------------------------------------------
__global__ __launch_bounds__(256) void gemm_bt_n64(
    const unsigned short* __restrict__ A, const unsigned short* __restrict__ Bt,
    const float* __restrict__ bias, const float* __restrict__ resid,
    float* __restrict__ outp, int M, int N, int K)
{
    __shared__ unsigned short As[2][128 * 64];
    __shared__ unsigned short Bs[2][64 * 64];
    const int tid  = threadIdx.x;
    const int lane = tid & 63;
    const int wid  = tid >> 6;
    int bx, by; xcd_remap(bx, by);
    const int brow = by << 7;
    const int bcol = bx << 6;

    f32x4 acc[2][4];
    const f32x4 zero = {0.f, 0.f, 0.f, 0.f};
#pragma unroll
    for (int m = 0; m < 2; ++m)
#pragma unroll
        for (int n = 0; n < 4; ++n) acc[m][n] = zero;

    const int nk = K >> 6;

    auto stage = [&](int buf, int k0) {
#pragma unroll
        for (int c = 0; c < 4; ++c) {           // A tile: 128*64 elems, 4 rounds
            int idx = (c << 11) + (tid << 3);
            int row = idx >> 6;
            int c8g = ((idx >> 3) & 7) ^ (row & 7);
            const unsigned short* ga = A + (size_t)(brow + row) * K + k0 + (c8g << 3);
            __builtin_amdgcn_global_load_lds(
                (const __attribute__((address_space(1))) unsigned int*)ga,
                (__attribute__((address_space(3))) unsigned int*)&As[buf][idx], 16, 0, 0);
        }
#pragma unroll
        for (int c = 0; c < 2; ++c) {           // B tile: 64*64 elems, 2 rounds
            int idx = (c << 11) + (tid << 3);
            int row = idx >> 6;
            int c8g = ((idx >> 3) & 7) ^ (row & 7);
            const unsigned short* gb = Bt + (size_t)(bcol + row) * K + k0 + (c8g << 3);
            __builtin_amdgcn_global_load_lds(
                (const __attribute__((address_space(1))) unsigned int*)gb,
                (__attribute__((address_space(3))) unsigned int*)&Bs[buf][idx], 16, 0, 0);
        }
    };

    stage(0, 0);
    for (int kt = 0; kt < nk; ++kt) {
        __syncthreads();
        if (kt + 1 < nk) stage((kt + 1) & 1, (kt + 1) << 6);
        const unsigned short* as = As[kt & 1];
        const unsigned short* bs = Bs[kt & 1];
        const int kg = lane >> 4;
#pragma unroll
        for (int f = 0; f < 2; ++f) {
            bf16x8 afr[2], bfr[4];
#pragma unroll
            for (int m = 0; m < 2; ++m) {
                int row = (wid << 5) + (m << 4) + (lane & 15);
                int c8  = ((f << 2) + kg) ^ (row & 7);
                afr[m] = *(const bf16x8*)&as[(row << 6) + (c8 << 3)];
            }
#pragma unroll
            for (int n = 0; n < 4; ++n) {
                int row = (n << 4) + (lane & 15);
                int c8  = ((f << 2) + kg) ^ (row & 7);
                bfr[n] = *(const bf16x8*)&bs[(row << 6) + (c8 << 3)];
            }
            __builtin_amdgcn_s_setprio(1);
#pragma unroll
            for (int m = 0; m < 2; ++m)
#pragma unroll
                for (int n = 0; n < 4; ++n)
                    acc[m][n] = mfma16(afr[m], bfr[n], acc[m][n]);
            __builtin_amdgcn_s_setprio(0);
        }
        __syncthreads();
    }

#pragma unroll
    for (int m = 0; m < 2; ++m)
#pragma unroll
        for (int n = 0; n < 4; ++n) {
            const int col = bcol + (n << 4) + (lane & 15);
            const float bv = bias[col];
#pragma unroll
            for (int r = 0; r < 4; ++r) {
                const int row = brow + (wid << 5) + (m << 4) + ((lane >> 4) << 2) + r;
                outp[(size_t)row * N + col] =
                    acc[m][n][r] + bv + resid[(size_t)row * N + col];
            }
        }
}

// ---------------------------------------------------------------------------
// LayerNorm (unbiased std, eps added to std), f32 in -> bf16 out
// ---------------------------------------------------------------------------
__global__ __launch_bounds__(256) void layernorm_k(
    const float* __restrict__ x, const float* __restrict__ sc,
    const float* __restrict__ sh, unsigned short* __restrict__ outp)
{
    const int row = blockIdx.x;
    const int tid = threadIdx.x;
    const float4 v = ((const float4*)(x + (size_t)row * EMB))[tid];
    float s  = v.x + v.y + v.z + v.w;
    float ss = v.x * v.x + v.y * v.y + v.z * v.z + v.w * v.w;
#pragma unroll
    for (int o = 32; o > 0; o >>= 1) {
        s  += __shfl_down(s, o);
        ss += __shfl_down(ss, o);
    }
    __shared__ float red[8];
    if ((tid & 63) == 0) { red[tid >> 6] = s; red[(tid >> 6) + 4] = ss; }
    __syncthreads();
    s  = red[0] + red[1] + red[2] + red[3];
    ss = red[4] + red[5] + red[6] + red[7];
    const float mean = s * (1.0f / EMB);
    const float var  = (ss - s * mean) * (1.0f / (EMB - 1));
    const float inv  = 1.0f / (sqrtf(var) + 1e-5f);
    const int c = tid << 2;
    ushort2 o01, o23;
    o01.x = f2bf((v.x - mean) * inv * sc[c + 0] + sh[c + 0]);
    o01.y = f2bf((v.y - mean) * inv * sc[c + 1] + sh[c + 1]);
    o23.x = f2bf((v.z - mean) * inv * sc[c + 2] + sh[c + 2]);
    o23.y = f2bf((v.w - mean) * inv * sc[c + 3] + sh[c + 3]);
    ushort4 o4 = {o01.x, o01.y, o23.x, o23.y};
    ((ushort4*)(outp + (size_t)row * EMB))[tid] = o4;
}

// ---------------------------------------------------------------------------
// V transpose per head: qkv V-part [s][d] -> vt[b][h][d][s]
// ---------------------------------------------------------------------------
__global__ __launch_bounds__(256) void vtrans_k(
    const unsigned short* __restrict__ qkv, unsigned short* __restrict__ vt)
{
    __shared__ unsigned short T[64 * 64];
    const int tid = threadIdx.x;
    const int st = blockIdx.x, h = blockIdx.y, b = blockIdx.z;
    const size_t rowbase = (size_t)b * SEQ;
    const unsigned short* vsrc = qkv + (rowbase + (st << 6)) * 3072 + 2 * EMB + h * 64;
#pragma unroll
    for (int it = 0; it < 2; ++it) {
        const int s  = (it << 5) + (tid >> 3);
        const int d8 = tid & 7;
        uint4 w = *(const uint4*)(vsrc + (size_t)s * 3072 + (d8 << 3));
        *(uint4*)&T[(s << 6) + ((d8 ^ (s & 7)) << 3)] = w;
    }
    __syncthreads();
    unsigned short* vdst = vt + ((size_t)(b * NHEAD + h) << 6) * SEQ + (st << 6);
#pragma unroll
    for (int it = 0; it < 2; ++it) {
        const int d  = (it << 5) + (tid >> 3);
        const int s8 = tid & 7;
        unsigned short o8[8];
#pragma unroll
        for (int j = 0; j < 8; ++j) {
            const int s = (s8 << 3) + j;
            o8[j] = T[(s << 6) + (((d >> 3) ^ (s & 7)) << 3) + (d & 7)];
        }
        *(uint4*)(vdst + (size_t)d * SEQ + (s8 << 3)) = *(const uint4*)o8;
    }
}

// ---------------------------------------------------------------------------
// Causal flash attention, swapped-QK^T wave-local softmax.
// Q pre-scaled by 0.125*log2e (folded into wq/bq at weight prep).
// Block = 4 waves; wave owns 16 q-rows; KV tiles of 64; double-buffered async
// staging. Lane owns one q-row (q = lane&15); S^T/P^T live lane-local.
// 1-D grid 512 decoded so all 16 blocks of one (b,h) share an XCD.
// ---------------------------------------------------------------------------
__global__ __launch_bounds__(256) void attn_k(
    const unsigned short* __restrict__ qkv, const unsigned short* __restrict__ vt,
    unsigned short* __restrict__ ctx)
{
    __shared__ unsigned short Ks[2][64 * 64];
    __shared__ unsigned short Vts[2][64 * 64];
    __shared__ unsigned short Ps[4][16 * 64];
    const int tid  = threadIdx.x;
    const int lane = tid & 63;
    const int wid  = tid >> 6;
    const int q    = lane & 15;        // this lane's q-row within the wave tile
    const int lg   = lane >> 4;        // lane group 0..3

    // XCD-grouped decode: same (b,h) -> same id mod 8 -> same XCD L2
    const int id = blockIdx.x;                 // 0..511
    const int xcd = id & 7, i = id >> 3;       // i 0..63
    const int grp = ((i >> 4) << 3) + xcd;     // 0..31
    const int pairi = i & 15;
    const int h = grp & 15;
    const int b = grp >> 4;

    const size_t rowbase = (size_t)b * SEQ;
    const unsigned short* kbase = qkv + rowbase * 3072 + EMB + h * 64;       // + s*3072
    const unsigned short* vbase = vt + ((size_t)(b * NHEAD + h) << 6) * SEQ; // [d][s]

    auto stage = [&](int buf, int t) {
#pragma unroll
        for (int c = 0; c < 2; ++c) {
            const int idx = (wid << 10) + (c << 9) + (lane << 3);   // elem in [64*64]
            {   // K tile: [kv][d], swizzled 8-elem slots
                const int kv  = idx >> 6;
                const int d8s = ((idx >> 3) & 7) ^ (kv & 7);
                const unsigned short* g = kbase + (size_t)((t << 6) + kv) * 3072 + (d8s << 3);
                __builtin_amdgcn_global_load_lds(
                    (const __attribute__((address_space(1))) unsigned int*)g,
                    (__attribute__((address_space(3))) unsigned int*)&Ks[buf][idx], 16, 0, 0);
            }
            {   // V^T tile: [d][s], swizzled
                const int d   = idx >> 6;
                const int s8s = ((idx >> 3) & 7) ^ (d & 7);
                const unsigned short* g = vbase + (size_t)d * SEQ + (t << 6) + (s8s << 3);
                __builtin_amdgcn_global_load_lds(
                    (const __attribute__((address_space(1))) unsigned int*)g,
                    (__attribute__((address_space(3))) unsigned int*)&Vts[buf][idx], 16, 0, 0);
            }
        }
    };

    const f32x4 zero = {0.f, 0.f, 0.f, 0.f};

#pragma unroll 1
    for (int pass = 0; pass < 2; ++pass) {
        const int qt = pass ? (31 - pairi) : pairi;
        const int qrow0 = (qt << 6) + (wid << 4);
        const int qglob = qrow0 + q;

        bf16x8 qf[2];
        {
            const unsigned short* qp = qkv + (rowbase + qglob) * 3072 + h * 64;
            qf[0] = *(const bf16x8*)&qp[(lg << 3)];
            qf[1] = *(const bf16x8*)&qp[32 + (lg << 3)];
        }

        f32x4 accd[4];                 // O^T: d = dg*16 + lg*4 + r, col q
#pragma unroll
        for (int dg = 0; dg < 4; ++dg) accd[dg] = zero;
        float mrow = -__builtin_inff();
        float lrow = 0.f;

        stage(0, 0);
#pragma unroll 1
        for (int t = 0; t <= qt; ++t) {
            __syncthreads();                   // buf (t&1) ready; prev compute done
            if (t < qt) stage((t + 1) & 1, t + 1);
            const unsigned short* ks = Ks[t & 1];
            const unsigned short* vs = Vts[t & 1];

            // S^T = (K Q^T): rows kv, cols q. Lane holds kv = g*16+lg*4+r for its q.
            f32x4 sg[4];
            __builtin_amdgcn_s_setprio(1);
#pragma unroll
            for (int g = 0; g < 4; ++g) {
                f32x4 sv = zero;
#pragma unroll
                for (int f = 0; f < 2; ++f) {
                    const int krow = (g << 4) + q;
                    const int cb   = (f << 5) + (lg << 3);
                    bf16x8 kf = *(const bf16x8*)&ks[(krow << 6) + (cb ^ ((krow & 7) << 3))];
                    sv = mfma16(kf, qf[f], sv);
                }
                sg[g] = sv;
            }
            __builtin_amdgcn_s_setprio(0);
            if (t == qt) {
#pragma unroll
                for (int g = 0; g < 4; ++g) {
#pragma unroll
                    for (int r = 0; r < 4; ++r) {
                        const int kvg = (t << 6) + (g << 4) + (lg << 2) + r;
                        if (kvg > qglob) sg[g][r] = -__builtin_inff();
                    }
                }
            }

            // wave-local online softmax (exp2 domain), balanced max tree
            float mg[4];
#pragma unroll
            for (int g = 0; g < 4; ++g)
                mg[g] = fmaxf(fmaxf(sg[g][0], sg[g][1]), fmaxf(sg[g][2], sg[g][3]));
            float mx = fmaxf(fmaxf(mg[0], mg[1]), fmaxf(mg[2], mg[3]));
            mx = fmaxf(mx, __shfl_xor(mx, 16));
            mx = fmaxf(mx, __shfl_xor(mx, 32));
            if (__any(mx > mrow + 8.0f)) {     // defer-max: rescale only on growth
                const float mn = fmaxf(mrow, mx);
                const float so = exp2f(mrow - mn);
                mrow = mn;
                lrow *= so;
#pragma unroll
                for (int dg = 0; dg < 4; ++dg) accd[dg] *= so;
            }
            float rs = 0.f;
#pragma unroll
            for (int g = 0; g < 4; ++g)
#pragma unroll
                for (int r = 0; r < 4; ++r) {
                    const float pv = exp2f(sg[g][r] - mrow);
                    sg[g][r] = pv;
                    rs += pv;
                }
            rs += __shfl_xor(rs, 16);
            rs += __shfl_xor(rs, 32);
            lrow += rs;

            // P -> LDS: row-major [q][kv], (q&7) XOR-swizzled 8-elem slots
#pragma unroll
            for (int g = 0; g < 4; ++g) {
                uint2 w;
                w.x = pack2bf(sg[g][0], sg[g][1]);
                w.y = pack2bf(sg[g][2], sg[g][3]);
                const int e = ((g << 4) + (lg << 2)) ^ ((q & 7) << 3);
                *(uint2*)&Ps[wid][(q << 6) + e] = w;
            }

            // O^T += V^T P : A = V^T rows d, B = P rows q
            bf16x8 pa[2];
#pragma unroll
            for (int f = 0; f < 2; ++f) {
                const int e = ((f << 5) + (lg << 3)) ^ ((q & 7) << 3);
                pa[f] = *(const bf16x8*)&Ps[wid][(q << 6) + e];
            }
            __builtin_amdgcn_s_setprio(1);
#pragma unroll
            for (int dg = 0; dg < 4; ++dg) {
#pragma unroll
                for (int f = 0; f < 2; ++f) {
                    const int vrow = (dg << 4) + q;
                    const int cb   = (f << 5) + (lg << 3);
                    bf16x8 vb = *(const bf16x8*)&vs[(vrow << 6) + (cb ^ ((vrow & 7) << 3))];
                    accd[dg] = mfma16(vb, pa[f], accd[dg]);
                }
            }
            __builtin_amdgcn_s_setprio(0);
        }

        const float inv = 1.0f / lrow;
        unsigned short* cp = ctx + (rowbase + qglob) * EMB + h * 64 + (lg << 2);
#pragma unroll
        for (int dg = 0; dg < 4; ++dg) {
            uint2 w;
            w.x = pack2bf(accd[dg][0] * inv, accd[dg][1] * inv);
            w.y = pack2bf(accd[dg][2] * inv, accd[dg][3] * inv);
            *(uint2*)(cp + (dg << 4)) = w;
        }
        __syncthreads();   // protect LDS bufs before next pass's stage(0,0)
    }
}

// ---------------------------------------------------------------------------
// W[K][N] f32 -> Wt[N][K] bf16 (tiled transpose), optional scale fold
// ---------------------------------------------------------------------------
__global__ __launch_bounds__(256) void transpose_cvt(
    const float* __restrict__ W, unsigned short* __restrict__ Wt, int K, int N,
    float scale)
{
    __shared__ float tbuf[32][33];
    const int n0 = blockIdx.x << 5;
    const int k0 = blockIdx.y << 5;
    const int tx = threadIdx.x & 31;
    const int ty = threadIdx.x >> 5;   // 0..7
#pragma unroll
    for (int j = 0; j < 32; j += 8)
        tbuf[ty + j][tx] = W[(size_t)(k0 + ty + j) * N + n0 + tx] * scale;
    __syncthreads();
#pragma unroll
    for (int j = 0; j < 32; j += 8)
        Wt[(size_t)(n0 + ty + j) * K + k0 + tx] = f2bf(tbuf[tx][ty + j]);
}

// q-part bias scaled by QSC (matches wq scale fold)
__global__ void pack_bias(const float* __restrict__ bq, const float* __restrict__ bk,
                          const float* __restrict__ bv, float* __restrict__ o,
                          float qsc)
{
    const int i = blockIdx.x * 256 + threadIdx.x;
    o[i] = (i < 1024) ? bq[i] * qsc : (i < 2048) ? bk[i - 1024] : bv[i - 2048];
}

// ---------------------------------------------------------------------------
extern "C" void kernel_launch(void* const* d_in, const int* in_sizes, int n_in,
                              void* d_out, int out_size, void* d_ws, size_t ws_size,
                              hipStream_t stream)
{
    const float* x   = (const float*)d_in[0];
    const float* l1s = (const float*)d_in[1];
    const float* l1b = (const float*)d_in[2];
    const float* l2s = (const float*)d_in[3];
    const float* l2b = (const float*)d_in[4];
    const float* wq  = (const float*)d_in[5];
    const float* bq  = (const float*)d_in[6];
    const float* wk  = (const float*)d_in[7];
    const float* bk  = (const float*)d_in[8];
    const float* wv  = (const float*)d_in[9];
    const float* bv  = (const float*)d_in[10];
    const float* wo  = (const float*)d_in[11];
    const float* bo  = (const float*)d_in[12];
    const float* wfc = (const float*)d_in[13];
    const float* bfc = (const float*)d_in[14];
    const float* wpr = (const float*)d_in[15];
    const float* bpr = (const float*)d_in[16];

    const float QSC = 0.18033688011112042f;   // 0.125 * log2(e)

    unsigned short* WtQKV = (unsigned short*)d_ws;                    // [3072][1024]
    unsigned short* WtO   = WtQKV + (size_t)3072 * 1024;              // [1024][1024]
    unsigned short* WtFC  = WtO   + (size_t)1024 * 1024;              // [4096][1024]
    unsigned short* WtPR  = WtFC  + (size_t)4096 * 1024;              // [1024][4096]
    unsigned short* LN1   = WtPR  + (size_t)1024 * 4096;              // [4096][1024]
    unsigned short* QKV   = LN1   + (size_t)4096 * 1024;              // [4096][3072]
    unsigned short* CTX   = QKV   + (size_t)4096 * 3072;              // [4096][1024]
    unsigned short* LN2   = CTX   + (size_t)4096 * 1024;              // [4096][1024]
    unsigned short* Gb    = LN2   + (size_t)4096 * 1024;              // [4096][4096]
    float* H    = (float*)(Gb + (size_t)4096 * 4096);                 // [4096][1024] f32
    float* BQKV = H + (size_t)4096 * 1024;                            // [3072]
    // VT aliases Gb: VT only live between vtrans_k and attn_k; Gb written later.
    unsigned short* VT = Gb;                                          // [2*16][64][2048]

    dim3 blk(256);
    transpose_cvt<<<dim3(32, 32), blk, 0, stream>>>(wq, WtQKV, 1024, 1024, QSC);
    transpose_cvt<<<dim3(32, 32), blk, 0, stream>>>(wk, WtQKV + (size_t)1024 * 1024, 1024, 1024, 1.0f);
    transpose_cvt<<<dim3(32, 32), blk, 0, stream>>>(wv, WtQKV + (size_t)2048 * 1024, 1024, 1024, 1.0f);
    transpose_cvt<<<dim3(32, 32), blk, 0, stream>>>(wo, WtO, 1024, 1024, 1.0f);
    transpose_cvt<<<dim3(128, 32), blk, 0, stream>>>(wfc, WtFC, 1024, 4096, 1.0f);
    transpose_cvt<<<dim3(32, 128), blk, 0, stream>>>(wpr, WtPR, 4096, 1024, 1.0f);
    pack_bias<<<dim3(12), blk, 0, stream>>>(bq, bk, bv, BQKV, QSC);

    layernorm_k<<<dim3(4096), blk, 0, stream>>>(x, l1s, l1b, LN1);
    gemm_bt<0><<<dim3(24, 32), blk, 0, stream>>>(LN1, WtQKV, BQKV, QKV, 4096, 3072, 1024);
    vtrans_k<<<dim3(32, NHEAD, 2), blk, 0, stream>>>(QKV, VT);
    attn_k<<<dim3(512), blk, 0, stream>>>(QKV, VT, CTX);
    // H = CTX @ WoT + bo + x   (BN=64/BK=64 tile, 512 blocks)
    gemm_bt_n64<<<dim3(16, 32), blk, 0, stream>>>(CTX, WtO, bo, x, H, 4096, 1024, 1024);
    layernorm_k<<<dim3(4096), blk, 0, stream>>>(H, l2s, l2b, LN2);
    gemm_bt<1><<<dim3(32, 32), blk, 0, stream>>>(LN2, WtFC, bfc, Gb, 4096, 4096, 1024);
    // d_out = Gb @ WprT + bpr + H   (BN=64/BK=64 tile, 512 blocks)
    gemm_bt_n64<<<dim3(16, 32), blk, 0, stream>>>(Gb, WtPR, bpr, H, (float*)d_out, 4096, 1024, 4096);
}